// Round 4
// baseline (389.885 us; speedup 1.0000x reference)
//
#include <hip/hip_runtime.h>

#define EMBED 1024
#define NH 16
#define HD 64
#define SEQ 2048
#define BATCH 2
#define ROWS (BATCH*SEQ)   // 4096
#define BHD (BATCH*NH)     // 32

typedef __bf16 bf16x8 __attribute__((ext_vector_type(8)));
typedef _Float16 f16x4 __attribute__((ext_vector_type(4)));
typedef float f32x4 __attribute__((ext_vector_type(4)));

__device__ __forceinline__ unsigned short f2bf(float f){
  union { float f; unsigned u; } v; v.f = f;
  unsigned r = v.u + 0x7fffu + ((v.u >> 16) & 1u);
  return (unsigned short)(r >> 16);
}
__device__ __forceinline__ float bf2f(unsigned short s){
  union { unsigned u; float f; } v; v.u = ((unsigned)s) << 16; return v.f;
}
__device__ __forceinline__ unsigned short f2h(float f){
  union { _Float16 h; unsigned short u; } v; v.h = (_Float16)f; return v.u;
}

// async global->LDS, 16B per lane; lds ptr must be wave-uniform base (lane*16 implicit)
typedef __attribute__((address_space(1))) unsigned int as1_t;
typedef __attribute__((address_space(3))) unsigned int as3_t;
__device__ __forceinline__ void async_ld16(void* gp, void* lp){
  __builtin_amdgcn_global_load_lds((as1_t*)gp, (as3_t*)lp, 16, 0, 0);
}

// ---------------- prep kernels ----------------

__global__ __launch_bounds__(256) void k_conv(const float* __restrict__ x,
                                              unsigned short* __restrict__ xb, int n4){
  int i = blockIdx.x * blockDim.x + threadIdx.x;
  if (i < n4){
    float4 f = ((const float4*)x)[i];
    ushort4 o;
    o.x = f2bf(f.x); o.y = f2bf(f.y); o.z = f2bf(f.z); o.w = f2bf(f.w);
    ((ushort4*)xb)[i] = o;
  }
}

// in[R][C] fp32 -> out[C][R] bf16
__global__ __launch_bounds__(256) void k_tr_f2b(const float* __restrict__ in,
                                                unsigned short* __restrict__ out, int R, int C){
  __shared__ float t[32][33];
  int c0 = blockIdx.x * 32, r0 = blockIdx.y * 32;
  int tx = threadIdx.x, ty = threadIdx.y;
  #pragma unroll
  for (int i = 0; i < 4; i++){ int r = ty + i*8; t[r][tx] = in[(size_t)(r0+r)*C + c0 + tx]; }
  __syncthreads();
  #pragma unroll
  for (int i = 0; i < 4; i++){ int rr = ty + i*8; out[(size_t)(c0+rr)*R + r0 + tx] = f2bf(t[tx][rr]); }
}

// batched 16-bit transpose: in[batch][R][C] -> out[batch][C][R]
__global__ __launch_bounds__(256) void k_tr_b2b(const unsigned short* __restrict__ in,
                                                unsigned short* __restrict__ out, int R, int C){
  in  += (size_t)blockIdx.z * R * C;
  out += (size_t)blockIdx.z * R * C;
  __shared__ unsigned short t[32][33];
  int c0 = blockIdx.x * 32, r0 = blockIdx.y * 32;
  int tx = threadIdx.x, ty = threadIdx.y;
  #pragma unroll
  for (int i = 0; i < 4; i++){ int r = ty + i*8; t[r][tx] = in[(size_t)(r0+r)*C + c0 + tx]; }
  __syncthreads();
  #pragma unroll
  for (int i = 0; i < 4; i++){ int rr = ty + i*8; out[(size_t)(c0+rr)*R + r0 + tx] = t[tx][rr]; }
}

// qn/kn from bf16-rounded q,k (keeps denominator = |q~ - k~|^2 >= 0)
__global__ __launch_bounds__(256) void k_norms(const unsigned short* __restrict__ q,
                                               const unsigned short* __restrict__ k,
                                               float* __restrict__ qn, float* __restrict__ kn){
  int i = blockIdx.x * blockDim.x + threadIdx.x;  // [0, 65536)
  const uint4* qr = (const uint4*)(q + (size_t)i * HD);
  const uint4* kr = (const uint4*)(k + (size_t)i * HD);
  float sq = 0.f, sk = 0.f;
  #pragma unroll
  for (int t = 0; t < 8; t++){
    uint4 uq = qr[t], uk = kr[t];
    unsigned aq[4] = {uq.x, uq.y, uq.z, uq.w};
    unsigned ak[4] = {uk.x, uk.y, uk.z, uk.w};
    #pragma unroll
    for (int j = 0; j < 4; j++){
      float f0 = bf2f((unsigned short)(aq[j] & 0xffff));
      float f1 = bf2f((unsigned short)(aq[j] >> 16));
      sq += f0*f0 + f1*f1;
      float g0 = bf2f((unsigned short)(ak[j] & 0xffff));
      float g1 = bf2f((unsigned short)(ak[j] >> 16));
      sk += g0*g0 + g1*g1;
    }
  }
  qn[i] = sq; kn[i] = sk;
}

// ---------------- GEMM1: 128x128 tile, global_load_lds staging ----------------

__global__ __launch_bounds__(256) void k_gemm_qkv(
    const unsigned short* __restrict__ A,    // [4096][1024] bf16
    const unsigned short* __restrict__ BT,   // [3072][1024] bf16
    const float* __restrict__ bias,          // [3072]
    unsigned short* __restrict__ qo, unsigned short* __restrict__ ko,
    unsigned short* __restrict__ vo)
{
  __shared__ __align__(16) unsigned short As[128*32];
  __shared__ __align__(16) unsigned short Bs[128*32];
  const int K = EMBED;
  int m0 = blockIdx.x * 128, n0 = blockIdx.y * 128;
  int tid = threadIdx.x, lane = tid & 63, wave = tid >> 6;
  int wm = wave >> 1, wn = wave & 1;
  int l16 = lane & 15, quad = lane >> 4;
  f32x4 acc[4][4] = {};
  int c0i = wave*64 + lane, c1i = 256 + wave*64 + lane;
  int r0 = c0i >> 2, cc0 = (c0i & 3) * 8;
  int r1 = c1i >> 2, cc1 = (c1i & 3) * 8;
  unsigned short* lA0 = &As[(wave*64)*8];
  unsigned short* lA1 = &As[(256 + wave*64)*8];
  unsigned short* lB0 = &Bs[(wave*64)*8];
  unsigned short* lB1 = &Bs[(256 + wave*64)*8];
  for (int k0 = 0; k0 < K; k0 += 32){
    async_ld16((void*)&A [(size_t)(m0 + r0)*K + k0 + cc0], (void*)lA0);
    async_ld16((void*)&A [(size_t)(m0 + r1)*K + k0 + cc1], (void*)lA1);
    async_ld16((void*)&BT[(size_t)(n0 + r0)*K + k0 + cc0], (void*)lB0);
    async_ld16((void*)&BT[(size_t)(n0 + r1)*K + k0 + cc1], (void*)lB1);
    __syncthreads();
    bf16x8 af[4], bfr[4];
    #pragma unroll
    for (int mi = 0; mi < 4; mi++) af[mi]  = *(const bf16x8*)&As[(wm*64 + mi*16 + l16)*32 + quad*8];
    #pragma unroll
    for (int ni = 0; ni < 4; ni++) bfr[ni] = *(const bf16x8*)&Bs[(wn*64 + ni*16 + l16)*32 + quad*8];
    #pragma unroll
    for (int mi = 0; mi < 4; mi++)
      #pragma unroll
      for (int ni = 0; ni < 4; ni++)
        acc[mi][ni] = __builtin_amdgcn_mfma_f32_16x16x32_bf16(af[mi], bfr[ni], acc[mi][ni], 0, 0, 0);
    __syncthreads();
  }
  #pragma unroll
  for (int mi = 0; mi < 4; mi++)
    #pragma unroll
    for (int ni = 0; ni < 4; ni++)
      #pragma unroll
      for (int rr = 0; rr < 4; rr++){
        int row = m0 + wm*64 + mi*16 + quad*4 + rr;
        int col = n0 + wn*64 + ni*16 + l16;
        float val = acc[mi][ni][rr] + bias[col];
        int b = row >> 11, l = row & 2047;
        int which = col >> 10, e = col & 1023, h = e >> 6, d = e & 63;
        unsigned short* dst = which == 0 ? qo : (which == 1 ? ko : vo);
        unsigned short bits = (which == 2) ? f2h(val) : f2bf(val);
        dst[(((size_t)(b*NH + h))*SEQ + l)*HD + d] = bits;
      }
}

// ---------------- attention: wave = (bh, q-tile, j-segment), flash-decoding split ----------------
// flat seg index per bh in [0,320): t<32 -> 1 seg; 32..63 -> 2; 64..95 -> 3; 96..127 -> 4.

__global__ __launch_bounds__(256) void k_attn(
    const unsigned short* __restrict__ qg,   // [BH][L][D] bf16
    const unsigned short* __restrict__ kg,   // [BH][L][D] bf16
    const unsigned short* __restrict__ vtg,  // [BH][D][L] f16
    const float* __restrict__ qn,
    const float* __restrict__ kn,
    unsigned short* __restrict__ attn_out,   // [ROWS][EMBED] bf16 (nseg==1 tiles only)
    _Float16* __restrict__ Op,               // [BHD*128*4][16][64] normalized partial O
    float* __restrict__ Mp,                  // [BHD*128*4][16]
    float* __restrict__ Lp)                  // [BHD*128*4][16]
{
  int bh = blockIdx.y; int b = bh >> 4, h = bh & 15;
  int tid = threadIdx.x, lane = tid & 63, wave = tid >> 6;
  int l16 = lane & 15, quad = lane >> 4;
  int f = blockIdx.x * 4 + wave;           // flat seg id in [0,320)
  int t, s;
  if (f < 32)       { t = f;                s = 0; }
  else if (f < 96)  { t = 32 + ((f-32)>>1); s = (f-32) & 1; }
  else if (f < 192) { t = 64 + (f-96)/3;    s = (f-96) % 3; }
  else              { t = 96 + ((f-192)>>2); s = (f-192) & 3; }
  int nseg = 1 + (t >> 5);
  int q0 = t * 16;
  int j_lo = s * 512;
  int j_hi = min(q0 + 16, j_lo + 512);

  const unsigned short* qbase = qg  + (size_t)bh * SEQ * HD;
  const unsigned short* kbase = kg  + (size_t)bh * SEQ * HD;
  const _Float16*       vtb   = (const _Float16*)vtg + (size_t)bh * HD * SEQ;
  const float* knb = kn + (size_t)bh * SEQ;

  auto load_blk = [&](int J, bf16x8 kd[2][2], f16x4 vd[4][2], float4 nd[2]){
    #pragma unroll
    for (int tile = 0; tile < 2; tile++)
      #pragma unroll
      for (int sk = 0; sk < 2; sk++)
        kd[tile][sk] = *(const bf16x8*)&kbase[(size_t)(J + tile*16 + l16)*HD + sk*32 + quad*8];
    #pragma unroll
    for (int g = 0; g < 4; g++)
      #pragma unroll
      for (int tile = 0; tile < 2; tile++)
        vd[g][tile] = *(const f16x4*)&vtb[(size_t)(g*16 + l16)*SEQ + J + tile*16 + quad*4];
    nd[0] = *(const float4*)&knb[J + quad*4];
    nd[1] = *(const float4*)&knb[J + 16 + quad*4];
  };

  bf16x8 aq[2];
  #pragma unroll
  for (int sk = 0; sk < 2; sk++)
    aq[sk] = *(const bf16x8*)&qbase[(size_t)(q0 + l16)*HD + sk*32 + quad*8];
  float qn_m = qn[(size_t)bh*SEQ + q0 + l16];

  float m_run = -1e30f, l_run = 0.f;     // per-lane: softmax row m = l16
  f32x4 oacc[4] = {};

  bf16x8 kc[2][2]; f16x4 vc[4][2]; float4 nc[2];
  load_blk(j_lo, kc, vc, nc);

  for (int j0 = j_lo; j0 < j_hi; j0 += 32){
    // prefetch next block into alt registers
    int jn = (j0 + 32 < j_hi) ? j0 + 32 : j0;
    bf16x8 kx[2][2]; f16x4 vx[4][2]; float4 nx[2];
    load_blk(jn, kx, vx, nx);

    // S^T: D = K(A) x Q(B); C-layout: col=m=l16, row=j=quad*4+rr
    f32x4 st[2] = {};
    #pragma unroll
    for (int tile = 0; tile < 2; tile++)
      #pragma unroll
      for (int sk = 0; sk < 2; sk++)
        st[tile] = __builtin_amdgcn_mfma_f32_16x16x32_bf16(kc[tile][sk], aq[sk], st[tile], 0, 0, 0);

    float kn_j[2][4] = {{nc[0].x, nc[0].y, nc[0].z, nc[0].w},
                        {nc[1].x, nc[1].y, nc[1].z, nc[1].w}};
    int mg = q0 + l16;
    float sc[2][4];
    if (j0 + 32 > q0){  // wave-uniform: diagonal block -> mask
      #pragma unroll
      for (int tile = 0; tile < 2; tile++)
        #pragma unroll
        for (int rr = 0; rr < 4; rr++){
          int jg = j0 + tile*16 + quad*4 + rr;
          float dot = st[tile][rr];
          float den = fmaxf(qn_m + kn_j[tile][rr] - 2.0f*dot, 0.0f) + 1e-6f;
          float v = dot * dot * __builtin_amdgcn_rcpf(den);
          sc[tile][rr] = (jg <= mg) ? v : -1e30f;
        }
    } else {
      #pragma unroll
      for (int tile = 0; tile < 2; tile++)
        #pragma unroll
        for (int rr = 0; rr < 4; rr++){
          float dot = st[tile][rr];
          float den = fmaxf(qn_m + kn_j[tile][rr] - 2.0f*dot, 0.0f) + 1e-6f;
          sc[tile][rr] = dot * dot * __builtin_amdgcn_rcpf(den);
        }
    }
    float mx = fmaxf(fmaxf(fmaxf(sc[0][0], sc[0][1]), fmaxf(sc[0][2], sc[0][3])),
                     fmaxf(fmaxf(sc[1][0], sc[1][1]), fmaxf(sc[1][2], sc[1][3])));
    mx = fmaxf(mx, __shfl_xor(mx, 16));
    mx = fmaxf(mx, __shfl_xor(mx, 32));
    float mnew = fmaxf(m_run, mx);
    float alpha = __expf(m_run - mnew);
    m_run = mnew;

    float ps = 0.f;
    #pragma unroll
    for (int tile = 0; tile < 2; tile++)
      #pragma unroll
      for (int rr = 0; rr < 4; rr++){
        float e = __expf(sc[tile][rr] - mnew);
        sc[tile][rr] = e; ps += e;
      }
    ps += __shfl_xor(ps, 16);
    ps += __shfl_xor(ps, 32);
    l_run = l_run * alpha + ps;

    float alpha_r[4];
    #pragma unroll
    for (int rr = 0; rr < 4; rr++) alpha_r[rr] = __shfl(alpha, quad*4 + rr);
    #pragma unroll
    for (int g = 0; g < 4; g++)
      #pragma unroll
      for (int rr = 0; rr < 4; rr++) oacc[g][rr] *= alpha_r[rr];

    // PV: P's S^T C-layout IS the 16x16x16 A-layout
    #pragma unroll
    for (int tile = 0; tile < 2; tile++){
      f16x4 ap;
      #pragma unroll
      for (int rr = 0; rr < 4; rr++) ap[rr] = (_Float16)sc[tile][rr];
      #pragma unroll
      for (int g = 0; g < 4; g++)
        oacc[g] = __builtin_amdgcn_mfma_f32_16x16x16f16(ap, vc[g][tile], oacc[g], 0, 0, 0);
    }

    // rotate buffers
    #pragma unroll
    for (int tile = 0; tile < 2; tile++)
      #pragma unroll
      for (int sk = 0; sk < 2; sk++) kc[tile][sk] = kx[tile][sk];
    #pragma unroll
    for (int g = 0; g < 4; g++)
      #pragma unroll
      for (int tile = 0; tile < 2; tile++) vc[g][tile] = vx[g][tile];
    nc[0] = nx[0]; nc[1] = nx[1];
  }

  float linv[4];
  #pragma unroll
  for (int rr = 0; rr < 4; rr++)
    linv[rr] = __builtin_amdgcn_rcpf(__shfl(l_run, quad*4 + rr));

  if (nseg == 1){
    #pragma unroll
    for (int g = 0; g < 4; g++)
      #pragma unroll
      for (int rr = 0; rr < 4; rr++){
        int lq = q0 + quad*4 + rr;
        attn_out[(size_t)(b*SEQ + lq)*EMBED + h*HD + g*16 + l16] = f2bf(oacc[g][rr] * linv[rr]);
      }
  } else {
    size_t pbase = (size_t)(bh*128 + t)*4 + s;
    #pragma unroll
    for (int g = 0; g < 4; g++)
      #pragma unroll
      for (int rr = 0; rr < 4; rr++)
        Op[pbase*1024 + (quad*4 + rr)*64 + g*16 + l16] = (_Float16)(oacc[g][rr] * linv[rr]);
    if (quad == 0){
      Mp[pbase*16 + l16] = m_run;
      Lp[pbase*16 + l16] = l_run;
    }
  }
}

// ---------------- combine partials for tiles t>=32 ----------------

__global__ __launch_bounds__(256) void k_combine(
    const _Float16* __restrict__ Op,
    const float* __restrict__ Mp,
    const float* __restrict__ Lp,
    unsigned short* __restrict__ attn_out)
{
  int t = 32 + blockIdx.x;        // 32..127
  int bh = blockIdx.y; int b = bh >> 4, h = bh & 15;
  int nseg = 1 + (t >> 5);        // 2..4
  size_t base = (size_t)(bh*128 + t)*4;
  __shared__ float sm[4][16], sl[4][16];
  int tid = threadIdx.x;
  if (tid < 64){
    int s = tid >> 4, r = tid & 15;
    sm[s][r] = (s < nseg) ? Mp[(base+s)*16 + r] : -1e30f;
    sl[s][r] = (s < nseg) ? Lp[(base+s)*16 + r] : 0.f;
  }
  __syncthreads();
  int d = tid & 63, r0 = tid >> 6;
  #pragma unroll
  for (int rr = 0; rr < 4; rr++){
    int r = r0*4 + rr;
    float m0 = sm[0][r], m1 = sm[1][r], m2 = sm[2][r], m3 = sm[3][r];
    float ms = fmaxf(fmaxf(m0, m1), fmaxf(m2, m3));
    float w0 = __expf(m0-ms)*sl[0][r], w1 = __expf(m1-ms)*sl[1][r];
    float w2 = __expf(m2-ms)*sl[2][r], w3 = __expf(m3-ms)*sl[3][r];
    float wsum = w0 + w1 + w2 + w3;
    float o = w0*(float)Op[(base+0)*1024 + r*64 + d]
            + w1*(float)Op[(base+1)*1024 + r*64 + d];
    if (nseg > 2) o += w2*(float)Op[(base+2)*1024 + r*64 + d];
    if (nseg > 3) o += w3*(float)Op[(base+3)*1024 + r*64 + d];
    int lq = t*16 + r;
    attn_out[(size_t)(b*SEQ + lq)*EMBED + h*HD + d] = f2bf(o / wsum);
  }
}

// ---------------- GEMM2: 128x128 tile, attn_out @ w_out + b_out -> fp32 ----------------

__global__ __launch_bounds__(256) void k_gemm_out(
    const unsigned short* __restrict__ A,    // [4096][1024] bf16
    const unsigned short* __restrict__ BT,   // [1024][1024] bf16
    const float* __restrict__ bias,          // [1024]
    float* __restrict__ out)
{
  __shared__ __align__(16) unsigned short As[128*32];
  __shared__ __align__(16) unsigned short Bs[128*32];
  const int K = EMBED;
  int m0 = blockIdx.x * 128, n0 = blockIdx.y * 128;
  int tid = threadIdx.x, lane = tid & 63, wave = tid >> 6;
  int wm = wave >> 1, wn = wave & 1;
  int l16 = lane & 15, quad = lane >> 4;
  f32x4 acc[4][4] = {};
  int c0i = wave*64 + lane, c1i = 256 + wave*64 + lane;
  int r0 = c0i >> 2, cc0 = (c0i & 3) * 8;
  int r1 = c1i >> 2, cc1 = (c1i & 3) * 8;
  unsigned short* lA0 = &As[(wave*64)*8];
  unsigned short* lA1 = &As[(256 + wave*64)*8];
  unsigned short* lB0 = &Bs[(wave*64)*8];
  unsigned short* lB1 = &Bs[(256 + wave*64)*8];
  for (int k0 = 0; k0 < K; k0 += 32){
    async_ld16((void*)&A [(size_t)(m0 + r0)*K + k0 + cc0], (void*)lA0);
    async_ld16((void*)&A [(size_t)(m0 + r1)*K + k0 + cc1], (void*)lA1);
    async_ld16((void*)&BT[(size_t)(n0 + r0)*K + k0 + cc0], (void*)lB0);
    async_ld16((void*)&BT[(size_t)(n0 + r1)*K + k0 + cc1], (void*)lB1);
    __syncthreads();
    bf16x8 af[4], bfr[4];
    #pragma unroll
    for (int mi = 0; mi < 4; mi++) af[mi]  = *(const bf16x8*)&As[(wm*64 + mi*16 + l16)*32 + quad*8];
    #pragma unroll
    for (int ni = 0; ni < 4; ni++) bfr[ni] = *(const bf16x8*)&Bs[(wn*64 + ni*16 + l16)*32 + quad*8];
    #pragma unroll
    for (int mi = 0; mi < 4; mi++)
      #pragma unroll
      for (int ni = 0; ni < 4; ni++)
        acc[mi][ni] = __builtin_amdgcn_mfma_f32_16x16x32_bf16(af[mi], bfr[ni], acc[mi][ni], 0, 0, 0);
    __syncthreads();
  }
  #pragma unroll
  for (int mi = 0; mi < 4; mi++)
    #pragma unroll
    for (int ni = 0; ni < 4; ni++)
      #pragma unroll
      for (int rr = 0; rr < 4; rr++){
        int row = m0 + wm*64 + mi*16 + quad*4 + rr;
        int col = n0 + wn*64 + ni*16 + l16;
        out[(size_t)row*EMBED + col] = acc[mi][ni][rr] + bias[col];
      }
}

// ---------------- launch ----------------

extern "C" void kernel_launch(void* const* d_in, const int* in_sizes, int n_in,
                              void* d_out, int out_size, void* d_ws, size_t ws_size,
                              hipStream_t stream) {
  const float* x     = (const float*)d_in[0];
  const float* w_qkv = (const float*)d_in[1];
  const float* b_qkv = (const float*)d_in[2];
  const float* w_out = (const float*)d_in[3];
  const float* b_out = (const float*)d_in[4];
  float* out = (float*)d_out;

  char* ws = (char*)d_ws;
  size_t off = 0;
  auto alloc = [&](size_t bytes) -> void* {
    void* p = ws + off; off += (bytes + 255) & ~(size_t)255; return p;
  };
  unsigned short* xb    = (unsigned short*)alloc((size_t)ROWS * EMBED * 2);      // 8 MB
  unsigned short* wqkvT = (unsigned short*)alloc((size_t)3 * EMBED * EMBED * 2); // 6 MB
  unsigned short* woutT = (unsigned short*)alloc((size_t)EMBED * EMBED * 2);     // 2 MB
  unsigned short* qb    = (unsigned short*)alloc((size_t)ROWS * EMBED * 2);
  unsigned short* kb    = (unsigned short*)alloc((size_t)ROWS * EMBED * 2);
  unsigned short* vb    = (unsigned short*)alloc((size_t)ROWS * EMBED * 2);      // f16 bits
  unsigned short* vTb   = (unsigned short*)alloc((size_t)ROWS * EMBED * 2);      // f16 bits
  float* qn = (float*)alloc((size_t)BHD * SEQ * 4);
  float* kn = (float*)alloc((size_t)BHD * SEQ * 4);
  _Float16* Op = (_Float16*)alloc((size_t)BHD * 128 * 4 * 1024 * 2);             // 33.5 MB
  float* Mp = (float*)alloc((size_t)BHD * 128 * 4 * 16 * 4);                     // 1 MB
  float* Lp = (float*)alloc((size_t)BHD * 128 * 4 * 16 * 4);                     // 1 MB
  unsigned short* attnb = xb;  // xb dead after GEMM1 — alias

  k_conv<<<dim3((ROWS*EMBED/4 + 255)/256), dim3(256), 0, stream>>>(x, xb, ROWS*EMBED/4);
  k_tr_f2b<<<dim3(3*EMBED/32, EMBED/32), dim3(32, 8), 0, stream>>>(w_qkv, wqkvT, EMBED, 3*EMBED);
  k_tr_f2b<<<dim3(EMBED/32, EMBED/32), dim3(32, 8), 0, stream>>>(w_out, woutT, EMBED, EMBED);
  k_gemm_qkv<<<dim3(ROWS/128, 3*EMBED/128), dim3(256), 0, stream>>>(xb, wqkvT, b_qkv, qb, kb, vb);
  k_norms<<<dim3(BHD*SEQ/256), dim3(256), 0, stream>>>(qb, kb, qn, kn);
  k_tr_b2b<<<dim3(HD/32, SEQ/32, BHD), dim3(32, 8), 0, stream>>>(vb, vTb, SEQ, HD);
  k_attn<<<dim3(80, BHD), dim3(256), 0, stream>>>(qb, kb, vTb, qn, kn, attnb, Op, Mp, Lp);
  k_combine<<<dim3(96, BHD), dim3(256), 0, stream>>>(Op, Mp, Lp, attnb);
  k_gemm_out<<<dim3(ROWS/128, EMBED/128), dim3(256), 0, stream>>>(attnb, woutT, b_out, out);
}

// Round 5
// 284.415 us; speedup vs baseline: 1.3708x; 1.3708x over previous
//
#include <hip/hip_runtime.h>

#define EMBED 1024
#define NH 16
#define HD 64
#define SEQ 2048
#define BATCH 2
#define ROWS (BATCH*SEQ)   // 4096
#define BHD (BATCH*NH)     // 32

typedef __bf16 bf16x8 __attribute__((ext_vector_type(8)));
typedef _Float16 f16x4 __attribute__((ext_vector_type(4)));
typedef float f32x4 __attribute__((ext_vector_type(4)));

__device__ __forceinline__ unsigned short f2bf(float f){
  union { float f; unsigned u; } v; v.f = f;
  unsigned r = v.u + 0x7fffu + ((v.u >> 16) & 1u);
  return (unsigned short)(r >> 16);
}
__device__ __forceinline__ float bf2f(unsigned short s){
  union { unsigned u; float f; } v; v.u = ((unsigned)s) << 16; return v.f;
}
__device__ __forceinline__ unsigned short f2h(float f){
  union { _Float16 h; unsigned short u; } v; v.h = (_Float16)f; return v.u;
}

// async global->LDS, 16B per lane; lds ptr must be wave-uniform base (lane*16 implicit)
typedef __attribute__((address_space(1))) unsigned int as1_t;
typedef __attribute__((address_space(3))) unsigned int as3_t;
__device__ __forceinline__ void async_ld16(const void* gp, void* lp){
  __builtin_amdgcn_global_load_lds((as1_t*)gp, (as3_t*)lp, 16, 0, 0);
}

// ---------------- prep kernels ----------------

__global__ __launch_bounds__(256) void k_conv(const float* __restrict__ x,
                                              unsigned short* __restrict__ xb, int n4){
  int i = blockIdx.x * blockDim.x + threadIdx.x;
  if (i < n4){
    float4 f = ((const float4*)x)[i];
    ushort4 o;
    o.x = f2bf(f.x); o.y = f2bf(f.y); o.z = f2bf(f.z); o.w = f2bf(f.w);
    ((ushort4*)xb)[i] = o;
  }
}

// in[R][C] fp32 -> out[C][R] bf16
__global__ __launch_bounds__(256) void k_tr_f2b(const float* __restrict__ in,
                                                unsigned short* __restrict__ out, int R, int C){
  __shared__ float t[32][33];
  int c0 = blockIdx.x * 32, r0 = blockIdx.y * 32;
  int tx = threadIdx.x, ty = threadIdx.y;
  #pragma unroll
  for (int i = 0; i < 4; i++){ int r = ty + i*8; t[r][tx] = in[(size_t)(r0+r)*C + c0 + tx]; }
  __syncthreads();
  #pragma unroll
  for (int i = 0; i < 4; i++){ int rr = ty + i*8; out[(size_t)(c0+rr)*R + r0 + tx] = f2bf(t[tx][rr]); }
}

// batched 16-bit transpose: in[batch][R][C] -> out[batch][C][R]
__global__ __launch_bounds__(256) void k_tr_b2b(const unsigned short* __restrict__ in,
                                                unsigned short* __restrict__ out, int R, int C){
  in  += (size_t)blockIdx.z * R * C;
  out += (size_t)blockIdx.z * R * C;
  __shared__ unsigned short t[32][33];
  int c0 = blockIdx.x * 32, r0 = blockIdx.y * 32;
  int tx = threadIdx.x, ty = threadIdx.y;
  #pragma unroll
  for (int i = 0; i < 4; i++){ int r = ty + i*8; t[r][tx] = in[(size_t)(r0+r)*C + c0 + tx]; }
  __syncthreads();
  #pragma unroll
  for (int i = 0; i < 4; i++){ int rr = ty + i*8; out[(size_t)(c0+rr)*R + r0 + tx] = t[tx][rr]; }
}

// qn/kn from bf16-rounded q,k (keeps denominator = |q~ - k~|^2 >= 0)
__global__ __launch_bounds__(256) void k_norms(const unsigned short* __restrict__ q,
                                               const unsigned short* __restrict__ k,
                                               float* __restrict__ qn, float* __restrict__ kn){
  int i = blockIdx.x * blockDim.x + threadIdx.x;  // [0, 65536)
  const uint4* qr = (const uint4*)(q + (size_t)i * HD);
  const uint4* kr = (const uint4*)(k + (size_t)i * HD);
  float sq = 0.f, sk = 0.f;
  #pragma unroll
  for (int t = 0; t < 8; t++){
    uint4 uq = qr[t], uk = kr[t];
    unsigned aq[4] = {uq.x, uq.y, uq.z, uq.w};
    unsigned ak[4] = {uk.x, uk.y, uk.z, uk.w};
    #pragma unroll
    for (int j = 0; j < 4; j++){
      float f0 = bf2f((unsigned short)(aq[j] & 0xffff));
      float f1 = bf2f((unsigned short)(aq[j] >> 16));
      sq += f0*f0 + f1*f1;
      float g0 = bf2f((unsigned short)(ak[j] & 0xffff));
      float g1 = bf2f((unsigned short)(ak[j] >> 16));
      sk += g0*g0 + g1*g1;
    }
  }
  qn[i] = sq; kn[i] = sk;
}

// ---------------- GEMM1: 128x128 tile, global_load_lds staging ----------------

__global__ __launch_bounds__(256) void k_gemm_qkv(
    const unsigned short* __restrict__ A,    // [4096][1024] bf16
    const unsigned short* __restrict__ BT,   // [3072][1024] bf16
    const float* __restrict__ bias,          // [3072]
    unsigned short* __restrict__ qo, unsigned short* __restrict__ ko,
    unsigned short* __restrict__ vo)
{
  __shared__ __align__(16) unsigned short As[128*32];
  __shared__ __align__(16) unsigned short Bs[128*32];
  const int K = EMBED;
  int m0 = blockIdx.x * 128, n0 = blockIdx.y * 128;
  int tid = threadIdx.x, lane = tid & 63, wave = tid >> 6;
  int wm = wave >> 1, wn = wave & 1;
  int l16 = lane & 15, quad = lane >> 4;
  f32x4 acc[4][4] = {};
  int c0i = wave*64 + lane, c1i = 256 + wave*64 + lane;
  int r0 = c0i >> 2, cc0 = (c0i & 3) * 8;
  int r1 = c1i >> 2, cc1 = (c1i & 3) * 8;
  unsigned short* lA0 = &As[(wave*64)*8];
  unsigned short* lA1 = &As[(256 + wave*64)*8];
  unsigned short* lB0 = &Bs[(wave*64)*8];
  unsigned short* lB1 = &Bs[(256 + wave*64)*8];
  for (int k0 = 0; k0 < K; k0 += 32){
    async_ld16((void*)&A [(size_t)(m0 + r0)*K + k0 + cc0], (void*)lA0);
    async_ld16((void*)&A [(size_t)(m0 + r1)*K + k0 + cc1], (void*)lA1);
    async_ld16((void*)&BT[(size_t)(n0 + r0)*K + k0 + cc0], (void*)lB0);
    async_ld16((void*)&BT[(size_t)(n0 + r1)*K + k0 + cc1], (void*)lB1);
    __syncthreads();
    bf16x8 af[4], bfr[4];
    #pragma unroll
    for (int mi = 0; mi < 4; mi++) af[mi]  = *(const bf16x8*)&As[(wm*64 + mi*16 + l16)*32 + quad*8];
    #pragma unroll
    for (int ni = 0; ni < 4; ni++) bfr[ni] = *(const bf16x8*)&Bs[(wn*64 + ni*16 + l16)*32 + quad*8];
    #pragma unroll
    for (int mi = 0; mi < 4; mi++)
      #pragma unroll
      for (int ni = 0; ni < 4; ni++)
        acc[mi][ni] = __builtin_amdgcn_mfma_f32_16x16x32_bf16(af[mi], bfr[ni], acc[mi][ni], 0, 0, 0);
    __syncthreads();
  }
  #pragma unroll
  for (int mi = 0; mi < 4; mi++)
    #pragma unroll
    for (int ni = 0; ni < 4; ni++)
      #pragma unroll
      for (int rr = 0; rr < 4; rr++){
        int row = m0 + wm*64 + mi*16 + quad*4 + rr;
        int col = n0 + wn*64 + ni*16 + l16;
        float val = acc[mi][ni][rr] + bias[col];
        int b = row >> 11, l = row & 2047;
        int which = col >> 10, e = col & 1023, h = e >> 6, d = e & 63;
        unsigned short* dst = which == 0 ? qo : (which == 1 ? ko : vo);
        unsigned short bits = (which == 2) ? f2h(val) : f2bf(val);
        dst[(((size_t)(b*NH + h))*SEQ + l)*HD + d] = bits;
      }
}

// ---------------- attention: block = 4 waves over 64 q-rows, LDS-staged K/V ----------------
// K LDS layout: 32 rows x 64 shorts, 16B slot s = j*8 + (o16 ^ (j&7))   [swizzled]
// V LDS layout: 64 rows x 32 f16,   16B slot s = d*4 + (c2 ^ (d&3))     [swizzled]

__global__ __launch_bounds__(256) void k_attn(
    const unsigned short* __restrict__ qg,   // [BH][L][D] bf16
    const unsigned short* __restrict__ kg,   // [BH][L][D] bf16
    const unsigned short* __restrict__ vtg,  // [BH][D][L] f16
    const float* __restrict__ qn,
    const float* __restrict__ kn,
    unsigned short* __restrict__ attn_out)   // [ROWS][EMBED] bf16
{
  __shared__ __align__(16) unsigned short Ks[2][2048];  // 2 x 4 KB
  __shared__ __align__(16) _Float16      Vs[2][2048];   // 2 x 4 KB
  int bh = blockIdx.y; int b = bh >> 4, h = bh & 15;
  int tid = threadIdx.x, lane = tid & 63, wave = tid >> 6;
  int l16 = lane & 15, quad = lane >> 4;
  int tb = 31 - blockIdx.x;            // heaviest block-tile first
  int qb = tb * 64;
  int q0 = qb + wave*16;               // this wave's 16 q-rows
  int jmax_w = q0 + 16;
  int jmax_b = qb + 64;

  const unsigned short* qbase = qg  + (size_t)bh * SEQ * HD;
  const unsigned short* kbase = kg  + (size_t)bh * SEQ * HD;
  const _Float16*       vtb   = (const _Float16*)vtg + (size_t)bh * HD * SEQ;
  const float* knb = kn + (size_t)bh * SEQ;

  // staging source indices: this thread stages 16B slot s = wave*64 + lane
  int sI = wave*64 + lane;
  int kj   = sI >> 3;                  // K row 0..31
  int ko16 = (sI & 7) ^ (kj & 7);      // global 16B col (swizzle inverse)
  int vd   = sI >> 2;                  // V row 0..63
  int vc2  = (sI & 3) ^ (vd & 3);      // global 16B col

  bf16x8 aq[2];
  #pragma unroll
  for (int sk = 0; sk < 2; sk++)
    aq[sk] = *(const bf16x8*)&qbase[(size_t)(q0 + l16)*HD + sk*32 + quad*8];
  float qn_m = qn[(size_t)bh*SEQ + q0 + l16];

  float m_run = -1e30f, l_run = 0.f;   // per-lane: softmax row m = l16
  f32x4 oacc[4] = {};

  // prologue stage of j-block 0 into buf 0
  async_ld16((const void*)&kbase[(size_t)kj*HD + ko16*8], (void*)&Ks[0][wave*512]);
  async_ld16((const void*)&vtb[(size_t)vd*SEQ + vc2*8],   (void*)&Vs[0][wave*512]);

  for (int j0 = 0; j0 < jmax_b; j0 += 32){
    int buf = (j0 >> 5) & 1;
    __syncthreads();   // drains vmcnt: buf is ready; prev compute on buf^1 done
    if (j0 + 32 < jmax_b){
      async_ld16((const void*)&kbase[(size_t)(j0 + 32 + kj)*HD + ko16*8], (void*)&Ks[buf^1][wave*512]);
      async_ld16((const void*)&vtb[(size_t)vd*SEQ + (j0 + 32) + vc2*8],   (void*)&Vs[buf^1][wave*512]);
    }
    if (j0 < jmax_w){
      // S^T: D = K(A) x Q(B); C-layout: col=m=l16, row=j=quad*4+rr
      f32x4 st[2] = {};
      #pragma unroll
      for (int tile = 0; tile < 2; tile++)
        #pragma unroll
        for (int sk = 0; sk < 2; sk++){
          bf16x8 ak = *(const bf16x8*)&Ks[buf][((tile*16 + l16)*8 + ((sk*4 + quad) ^ (l16 & 7)))*8];
          st[tile] = __builtin_amdgcn_mfma_f32_16x16x32_bf16(ak, aq[sk], st[tile], 0, 0, 0);
        }
      float4 kn_a = *(const float4*)&knb[j0 + quad*4];
      float4 kn_b = *(const float4*)&knb[j0 + 16 + quad*4];
      float kn_j[2][4] = {{kn_a.x, kn_a.y, kn_a.z, kn_a.w}, {kn_b.x, kn_b.y, kn_b.z, kn_b.w}};
      int mg = q0 + l16;
      float sc[2][4];
      if (j0 + 32 > q0){  // wave-uniform: diagonal block -> mask
        #pragma unroll
        for (int tile = 0; tile < 2; tile++)
          #pragma unroll
          for (int rr = 0; rr < 4; rr++){
            int jg = j0 + tile*16 + quad*4 + rr;
            float dot = st[tile][rr];
            float den = fmaxf(qn_m + kn_j[tile][rr] - 2.0f*dot, 0.0f) + 1e-6f;
            float v = dot * dot * __builtin_amdgcn_rcpf(den);
            sc[tile][rr] = (jg <= mg) ? v : -1e30f;
          }
      } else {
        #pragma unroll
        for (int tile = 0; tile < 2; tile++)
          #pragma unroll
          for (int rr = 0; rr < 4; rr++){
            float dot = st[tile][rr];
            float den = fmaxf(qn_m + kn_j[tile][rr] - 2.0f*dot, 0.0f) + 1e-6f;
            sc[tile][rr] = dot * dot * __builtin_amdgcn_rcpf(den);
          }
      }
      float mx = fmaxf(fmaxf(fmaxf(sc[0][0], sc[0][1]), fmaxf(sc[0][2], sc[0][3])),
                       fmaxf(fmaxf(sc[1][0], sc[1][1]), fmaxf(sc[1][2], sc[1][3])));
      mx = fmaxf(mx, __shfl_xor(mx, 16));
      mx = fmaxf(mx, __shfl_xor(mx, 32));
      float mnew = fmaxf(m_run, mx);
      float alpha = __expf(m_run - mnew);
      m_run = mnew;

      float ps = 0.f;
      #pragma unroll
      for (int tile = 0; tile < 2; tile++)
        #pragma unroll
        for (int rr = 0; rr < 4; rr++){
          float e = __expf(sc[tile][rr] - mnew);
          sc[tile][rr] = e; ps += e;
        }
      ps += __shfl_xor(ps, 16);
      ps += __shfl_xor(ps, 32);
      l_run = l_run * alpha + ps;

      float alpha_r[4];
      #pragma unroll
      for (int rr = 0; rr < 4; rr++) alpha_r[rr] = __shfl(alpha, quad*4 + rr);
      #pragma unroll
      for (int g = 0; g < 4; g++)
        #pragma unroll
        for (int rr = 0; rr < 4; rr++) oacc[g][rr] *= alpha_r[rr];

      // PV: P's S^T C-layout IS the 16x16x16 A-layout
      #pragma unroll
      for (int tile = 0; tile < 2; tile++){
        f16x4 ap;
        #pragma unroll
        for (int rr = 0; rr < 4; rr++) ap[rr] = (_Float16)sc[tile][rr];
        #pragma unroll
        for (int g = 0; g < 4; g++){
          f16x4 bv = *(const f16x4*)&Vs[buf][(g*16 + l16)*32 + (((tile*2 + (quad>>1)) ^ (l16 & 3))*8) + (quad & 1)*4];
          oacc[g] = __builtin_amdgcn_mfma_f32_16x16x16f16(ap, bv, oacc[g], 0, 0, 0);
        }
      }
    }
  }

  float linv[4];
  #pragma unroll
  for (int rr = 0; rr < 4; rr++)
    linv[rr] = __builtin_amdgcn_rcpf(__shfl(l_run, quad*4 + rr));
  #pragma unroll
  for (int g = 0; g < 4; g++)
    #pragma unroll
    for (int rr = 0; rr < 4; rr++){
      int lq = q0 + quad*4 + rr;
      attn_out[(size_t)(b*SEQ + lq)*EMBED + h*HD + g*16 + l16] = f2bf(oacc[g][rr] * linv[rr]);
    }
}

// ---------------- GEMM2: 128x128 tile, attn_out @ w_out + b_out -> fp32 ----------------

__global__ __launch_bounds__(256) void k_gemm_out(
    const unsigned short* __restrict__ A,    // [4096][1024] bf16
    const unsigned short* __restrict__ BT,   // [1024][1024] bf16
    const float* __restrict__ bias,          // [1024]
    float* __restrict__ out)
{
  __shared__ __align__(16) unsigned short As[128*32];
  __shared__ __align__(16) unsigned short Bs[128*32];
  const int K = EMBED;
  int m0 = blockIdx.x * 128, n0 = blockIdx.y * 128;
  int tid = threadIdx.x, lane = tid & 63, wave = tid >> 6;
  int wm = wave >> 1, wn = wave & 1;
  int l16 = lane & 15, quad = lane >> 4;
  f32x4 acc[4][4] = {};
  int c0i = wave*64 + lane, c1i = 256 + wave*64 + lane;
  int r0 = c0i >> 2, cc0 = (c0i & 3) * 8;
  int r1 = c1i >> 2, cc1 = (c1i & 3) * 8;
  unsigned short* lA0 = &As[(wave*64)*8];
  unsigned short* lA1 = &As[(256 + wave*64)*8];
  unsigned short* lB0 = &Bs[(wave*64)*8];
  unsigned short* lB1 = &Bs[(256 + wave*64)*8];
  for (int k0 = 0; k0 < K; k0 += 32){
    async_ld16((void*)&A [(size_t)(m0 + r0)*K + k0 + cc0], (void*)lA0);
    async_ld16((void*)&A [(size_t)(m0 + r1)*K + k0 + cc1], (void*)lA1);
    async_ld16((void*)&BT[(size_t)(n0 + r0)*K + k0 + cc0], (void*)lB0);
    async_ld16((void*)&BT[(size_t)(n0 + r1)*K + k0 + cc1], (void*)lB1);
    __syncthreads();
    bf16x8 af[4], bfr[4];
    #pragma unroll
    for (int mi = 0; mi < 4; mi++) af[mi]  = *(const bf16x8*)&As[(wm*64 + mi*16 + l16)*32 + quad*8];
    #pragma unroll
    for (int ni = 0; ni < 4; ni++) bfr[ni] = *(const bf16x8*)&Bs[(wn*64 + ni*16 + l16)*32 + quad*8];
    #pragma unroll
    for (int mi = 0; mi < 4; mi++)
      #pragma unroll
      for (int ni = 0; ni < 4; ni++)
        acc[mi][ni] = __builtin_amdgcn_mfma_f32_16x16x32_bf16(af[mi], bfr[ni], acc[mi][ni], 0, 0, 0);
    __syncthreads();
  }
  #pragma unroll
  for (int mi = 0; mi < 4; mi++)
    #pragma unroll
    for (int ni = 0; ni < 4; ni++)
      #pragma unroll
      for (int rr = 0; rr < 4; rr++){
        int row = m0 + wm*64 + mi*16 + quad*4 + rr;
        int col = n0 + wn*64 + ni*16 + l16;
        out[(size_t)row*EMBED + col] = acc[mi][ni][rr] + bias[col];
      }
}

// ---------------- launch ----------------

extern "C" void kernel_launch(void* const* d_in, const int* in_sizes, int n_in,
                              void* d_out, int out_size, void* d_ws, size_t ws_size,
                              hipStream_t stream) {
  const float* x     = (const float*)d_in[0];
  const float* w_qkv = (const float*)d_in[1];
  const float* b_qkv = (const float*)d_in[2];
  const float* w_out = (const float*)d_in[3];
  const float* b_out = (const float*)d_in[4];
  float* out = (float*)d_out;

  char* ws = (char*)d_ws;
  size_t off = 0;
  auto alloc = [&](size_t bytes) -> void* {
    void* p = ws + off; off += (bytes + 255) & ~(size_t)255; return p;
  };
  unsigned short* xb    = (unsigned short*)alloc((size_t)ROWS * EMBED * 2);      // 8 MB
  unsigned short* wqkvT = (unsigned short*)alloc((size_t)3 * EMBED * EMBED * 2); // 6 MB
  unsigned short* woutT = (unsigned short*)alloc((size_t)EMBED * EMBED * 2);     // 2 MB
  unsigned short* qb    = (unsigned short*)alloc((size_t)ROWS * EMBED * 2);
  unsigned short* kb    = (unsigned short*)alloc((size_t)ROWS * EMBED * 2);
  unsigned short* vb    = (unsigned short*)alloc((size_t)ROWS * EMBED * 2);      // f16 bits
  unsigned short* vTb   = (unsigned short*)alloc((size_t)ROWS * EMBED * 2);      // f16 bits
  float* qn = (float*)alloc((size_t)BHD * SEQ * 4);
  float* kn = (float*)alloc((size_t)BHD * SEQ * 4);
  unsigned short* attnb = xb;  // xb dead after GEMM1 — alias

  k_conv<<<dim3((ROWS*EMBED/4 + 255)/256), dim3(256), 0, stream>>>(x, xb, ROWS*EMBED/4);
  k_tr_f2b<<<dim3(3*EMBED/32, EMBED/32), dim3(32, 8), 0, stream>>>(w_qkv, wqkvT, EMBED, 3*EMBED);
  k_tr_f2b<<<dim3(EMBED/32, EMBED/32), dim3(32, 8), 0, stream>>>(w_out, woutT, EMBED, EMBED);
  k_gemm_qkv<<<dim3(ROWS/128, 3*EMBED/128), dim3(256), 0, stream>>>(xb, wqkvT, b_qkv, qb, kb, vb);
  k_norms<<<dim3(BHD*SEQ/256), dim3(256), 0, stream>>>(qb, kb, qn, kn);
  k_tr_b2b<<<dim3(HD/32, SEQ/32, BHD), dim3(32, 8), 0, stream>>>(vb, vTb, SEQ, HD);
  k_attn<<<dim3(32, BHD), dim3(256), 0, stream>>>(qb, kb, vTb, qn, kn, attnb);
  k_gemm_out<<<dim3(ROWS/128, EMBED/128), dim3(256), 0, stream>>>(attnb, woutT, b_out, out);
}

// Round 6
// 271.249 us; speedup vs baseline: 1.4374x; 1.0485x over previous
//
#include <hip/hip_runtime.h>

#define EMBED 1024
#define NH 16
#define HD 64
#define SEQ 2048
#define BATCH 2
#define ROWS (BATCH*SEQ)   // 4096
#define BHD (BATCH*NH)     // 32

typedef __bf16 bf16x8 __attribute__((ext_vector_type(8)));
typedef _Float16 f16x4 __attribute__((ext_vector_type(4)));
typedef float f32x4 __attribute__((ext_vector_type(4)));

__device__ __forceinline__ unsigned short f2bf(float f){
  union { float f; unsigned u; } v; v.f = f;
  unsigned r = v.u + 0x7fffu + ((v.u >> 16) & 1u);
  return (unsigned short)(r >> 16);
}
__device__ __forceinline__ float bf2f(unsigned short s){
  union { unsigned u; float f; } v; v.u = ((unsigned)s) << 16; return v.f;
}
__device__ __forceinline__ unsigned short f2h(float f){
  union { _Float16 h; unsigned short u; } v; v.h = (_Float16)f; return v.u;
}

// async global->LDS, 16B per lane; lds ptr must be wave-uniform base (lane*16 implicit)
typedef __attribute__((address_space(1))) unsigned int as1_t;
typedef __attribute__((address_space(3))) unsigned int as3_t;
__device__ __forceinline__ void async_ld16(const void* gp, void* lp){
  __builtin_amdgcn_global_load_lds((as1_t*)gp, (as3_t*)lp, 16, 0, 0);
}

// ---------------- prep kernels ----------------

__global__ __launch_bounds__(256) void k_conv(const float* __restrict__ x,
                                              unsigned short* __restrict__ xb, int n4){
  int i = blockIdx.x * blockDim.x + threadIdx.x;
  if (i < n4){
    float4 f = ((const float4*)x)[i];
    ushort4 o;
    o.x = f2bf(f.x); o.y = f2bf(f.y); o.z = f2bf(f.z); o.w = f2bf(f.w);
    ((ushort4*)xb)[i] = o;
  }
}

// in[R][C] fp32 -> out[C][R] bf16
__global__ __launch_bounds__(256) void k_tr_f2b(const float* __restrict__ in,
                                                unsigned short* __restrict__ out, int R, int C){
  __shared__ float t[32][33];
  int c0 = blockIdx.x * 32, r0 = blockIdx.y * 32;
  int tx = threadIdx.x, ty = threadIdx.y;
  #pragma unroll
  for (int i = 0; i < 4; i++){ int r = ty + i*8; t[r][tx] = in[(size_t)(r0+r)*C + c0 + tx]; }
  __syncthreads();
  #pragma unroll
  for (int i = 0; i < 4; i++){ int rr = ty + i*8; out[(size_t)(c0+rr)*R + r0 + tx] = f2bf(t[tx][rr]); }
}

// batched 16-bit transpose: in[batch][R][C] -> out[batch][C][R]
__global__ __launch_bounds__(256) void k_tr_b2b(const unsigned short* __restrict__ in,
                                                unsigned short* __restrict__ out, int R, int C){
  in  += (size_t)blockIdx.z * R * C;
  out += (size_t)blockIdx.z * R * C;
  __shared__ unsigned short t[32][33];
  int c0 = blockIdx.x * 32, r0 = blockIdx.y * 32;
  int tx = threadIdx.x, ty = threadIdx.y;
  #pragma unroll
  for (int i = 0; i < 4; i++){ int r = ty + i*8; t[r][tx] = in[(size_t)(r0+r)*C + c0 + tx]; }
  __syncthreads();
  #pragma unroll
  for (int i = 0; i < 4; i++){ int rr = ty + i*8; out[(size_t)(c0+rr)*R + r0 + tx] = t[tx][rr]; }
}

// qn/kn from bf16-rounded q,k (keeps denominator = |q~ - k~|^2 >= 0)
__global__ __launch_bounds__(256) void k_norms(const unsigned short* __restrict__ q,
                                               const unsigned short* __restrict__ k,
                                               float* __restrict__ qn, float* __restrict__ kn){
  int i = blockIdx.x * blockDim.x + threadIdx.x;  // [0, 65536)
  const uint4* qr = (const uint4*)(q + (size_t)i * HD);
  const uint4* kr = (const uint4*)(k + (size_t)i * HD);
  float sq = 0.f, sk = 0.f;
  #pragma unroll
  for (int t = 0; t < 8; t++){
    uint4 uq = qr[t], uk = kr[t];
    unsigned aq[4] = {uq.x, uq.y, uq.z, uq.w};
    unsigned ak[4] = {uk.x, uk.y, uk.z, uk.w};
    #pragma unroll
    for (int j = 0; j < 4; j++){
      float f0 = bf2f((unsigned short)(aq[j] & 0xffff));
      float f1 = bf2f((unsigned short)(aq[j] >> 16));
      sq += f0*f0 + f1*f1;
      float g0 = bf2f((unsigned short)(ak[j] & 0xffff));
      float g1 = bf2f((unsigned short)(ak[j] >> 16));
      sk += g0*g0 + g1*g1;
    }
  }
  qn[i] = sq; kn[i] = sk;
}

// ---------------- GEMM1: 128x128 tile, global_load_lds staging ----------------

__global__ __launch_bounds__(256) void k_gemm_qkv(
    const unsigned short* __restrict__ A,    // [4096][1024] bf16
    const unsigned short* __restrict__ BT,   // [3072][1024] bf16
    const float* __restrict__ bias,          // [3072]
    unsigned short* __restrict__ qo, unsigned short* __restrict__ ko,
    unsigned short* __restrict__ vo)
{
  __shared__ __align__(16) unsigned short As[128*32];
  __shared__ __align__(16) unsigned short Bs[128*32];
  const int K = EMBED;
  int m0 = blockIdx.x * 128, n0 = blockIdx.y * 128;
  int tid = threadIdx.x, lane = tid & 63, wave = tid >> 6;
  int wm = wave >> 1, wn = wave & 1;
  int l16 = lane & 15, quad = lane >> 4;
  f32x4 acc[4][4] = {};
  int c0i = wave*64 + lane, c1i = 256 + wave*64 + lane;
  int r0 = c0i >> 2, cc0 = (c0i & 3) * 8;
  int r1 = c1i >> 2, cc1 = (c1i & 3) * 8;
  unsigned short* lA0 = &As[(wave*64)*8];
  unsigned short* lA1 = &As[(256 + wave*64)*8];
  unsigned short* lB0 = &Bs[(wave*64)*8];
  unsigned short* lB1 = &Bs[(256 + wave*64)*8];
  for (int k0 = 0; k0 < K; k0 += 32){
    async_ld16((void*)&A [(size_t)(m0 + r0)*K + k0 + cc0], (void*)lA0);
    async_ld16((void*)&A [(size_t)(m0 + r1)*K + k0 + cc1], (void*)lA1);
    async_ld16((void*)&BT[(size_t)(n0 + r0)*K + k0 + cc0], (void*)lB0);
    async_ld16((void*)&BT[(size_t)(n0 + r1)*K + k0 + cc1], (void*)lB1);
    __syncthreads();
    bf16x8 af[4], bfr[4];
    #pragma unroll
    for (int mi = 0; mi < 4; mi++) af[mi]  = *(const bf16x8*)&As[(wm*64 + mi*16 + l16)*32 + quad*8];
    #pragma unroll
    for (int ni = 0; ni < 4; ni++) bfr[ni] = *(const bf16x8*)&Bs[(wn*64 + ni*16 + l16)*32 + quad*8];
    #pragma unroll
    for (int mi = 0; mi < 4; mi++)
      #pragma unroll
      for (int ni = 0; ni < 4; ni++)
        acc[mi][ni] = __builtin_amdgcn_mfma_f32_16x16x32_bf16(af[mi], bfr[ni], acc[mi][ni], 0, 0, 0);
    __syncthreads();
  }
  #pragma unroll
  for (int mi = 0; mi < 4; mi++)
    #pragma unroll
    for (int ni = 0; ni < 4; ni++)
      #pragma unroll
      for (int rr = 0; rr < 4; rr++){
        int row = m0 + wm*64 + mi*16 + quad*4 + rr;
        int col = n0 + wn*64 + ni*16 + l16;
        float val = acc[mi][ni][rr] + bias[col];
        int b = row >> 11, l = row & 2047;
        int which = col >> 10, e = col & 1023, h = e >> 6, d = e & 63;
        unsigned short* dst = which == 0 ? qo : (which == 1 ? ko : vo);
        unsigned short bits = (which == 2) ? f2h(val) : f2bf(val);
        dst[(((size_t)(b*NH + h))*SEQ + l)*HD + d] = bits;
      }
}

// ---------------- attention: block = 4 waves over 64 q-rows, LDS K/V, O^T accumulation ----------------
// S^T = K x Q^T (C-layout: m on l16, j on quad*4+rr)
// O^T = V^T x P^T via mfma_16x16x16f16(A=V^T-frag, B=P^T-frag==S^T C-layout, C=O^T)
// -> softmax row m lives on l16 EVERYWHERE: alpha/l/linv all per-lane.

__global__ __launch_bounds__(256) void k_attn(
    const unsigned short* __restrict__ qg,   // [BH][L][D] bf16
    const unsigned short* __restrict__ kg,   // [BH][L][D] bf16
    const unsigned short* __restrict__ vtg,  // [BH][D][L] f16
    const float* __restrict__ qn,
    const float* __restrict__ kn,
    unsigned short* __restrict__ attn_out)   // [ROWS][EMBED] bf16
{
  __shared__ __align__(16) unsigned short Ks[2][2048];  // 2 x 4 KB
  __shared__ __align__(16) _Float16      Vs[2][2048];   // 2 x 4 KB
  int bh = blockIdx.y; int b = bh >> 4, h = bh & 15;
  int tid = threadIdx.x, lane = tid & 63, wave = tid >> 6;
  int l16 = lane & 15, quad = lane >> 4;
  int tb = 31 - blockIdx.x;            // heaviest block-tile first
  int qb = tb * 64;
  int q0 = qb + wave*16;               // this wave's 16 q-rows
  int jmax_w = q0 + 16;
  int jmax_b = qb + 64;

  const unsigned short* qbase = qg  + (size_t)bh * SEQ * HD;
  const unsigned short* kbase = kg  + (size_t)bh * SEQ * HD;
  const _Float16*       vtb   = (const _Float16*)vtg + (size_t)bh * HD * SEQ;
  const float* knb = kn + (size_t)bh * SEQ;

  // staging: thread stages 16B slot sI = wave*64 + lane
  int sI = wave*64 + lane;
  int kj   = sI >> 3;                  // K row 0..31
  int ko16 = (sI & 7) ^ (kj & 7);      // global 16B col (swizzle inverse)
  int vd   = sI >> 2;                  // V row 0..63
  int vc2  = (sI & 3) ^ (vd & 3);      // global 16B col

  bf16x8 aq[2];
  #pragma unroll
  for (int sk = 0; sk < 2; sk++)
    aq[sk] = *(const bf16x8*)&qbase[(size_t)(q0 + l16)*HD + sk*32 + quad*8];
  float qn_m = qn[(size_t)bh*SEQ + q0 + l16];

  float m_run = -1e30f, l_lane = 0.f;  // per-lane: softmax row m = l16; l partial over this lane's j's
  f32x4 oacc[4] = {};                  // O^T: row d = g*16+quad*4+rr, col m = l16

  // prologue stage of j-block 0 into buf 0
  async_ld16((const void*)&kbase[(size_t)kj*HD + ko16*8], (void*)&Ks[0][wave*512]);
  async_ld16((const void*)&vtb[(size_t)vd*SEQ + vc2*8],   (void*)&Vs[0][wave*512]);

  for (int j0 = 0; j0 < jmax_b; j0 += 32){
    int buf = (j0 >> 5) & 1;
    __syncthreads();   // buf ready; prev compute on buf^1 done
    if (j0 + 32 < jmax_b){
      async_ld16((const void*)&kbase[(size_t)(j0 + 32 + kj)*HD + ko16*8], (void*)&Ks[buf^1][wave*512]);
      async_ld16((const void*)&vtb[(size_t)vd*SEQ + (j0 + 32) + vc2*8],   (void*)&Vs[buf^1][wave*512]);
    }
    if (j0 < jmax_w){
      // S^T: D = K(A) x Q(B)
      f32x4 st[2] = {};
      #pragma unroll
      for (int tile = 0; tile < 2; tile++)
        #pragma unroll
        for (int sk = 0; sk < 2; sk++){
          bf16x8 ak = *(const bf16x8*)&Ks[buf][((tile*16 + l16)*8 + ((sk*4 + quad) ^ (l16 & 7)))*8];
          st[tile] = __builtin_amdgcn_mfma_f32_16x16x32_bf16(ak, aq[sk], st[tile], 0, 0, 0);
        }
      float4 kn_a = *(const float4*)&knb[j0 + quad*4];
      float4 kn_b = *(const float4*)&knb[j0 + 16 + quad*4];
      float kn_j[2][4] = {{kn_a.x, kn_a.y, kn_a.z, kn_a.w}, {kn_b.x, kn_b.y, kn_b.z, kn_b.w}};
      int mg = q0 + l16;
      float sc[2][4];
      if (j0 + 32 > q0){  // wave-uniform: diagonal block -> mask
        #pragma unroll
        for (int tile = 0; tile < 2; tile++)
          #pragma unroll
          for (int rr = 0; rr < 4; rr++){
            int jg = j0 + tile*16 + quad*4 + rr;
            float dot = st[tile][rr];
            float den = fmaxf(qn_m + kn_j[tile][rr] - 2.0f*dot, 0.0f) + 1e-6f;
            float v = dot * dot * __builtin_amdgcn_rcpf(den);
            sc[tile][rr] = (jg <= mg) ? v : -1e30f;
          }
      } else {
        #pragma unroll
        for (int tile = 0; tile < 2; tile++)
          #pragma unroll
          for (int rr = 0; rr < 4; rr++){
            float dot = st[tile][rr];
            float den = fmaxf(qn_m + kn_j[tile][rr] - 2.0f*dot, 0.0f) + 1e-6f;
            sc[tile][rr] = dot * dot * __builtin_amdgcn_rcpf(den);
          }
      }
      // row max: in-lane over 8, then cross-quad (the ONLY cross-lane ops in the loop)
      float mx = fmaxf(fmaxf(fmaxf(sc[0][0], sc[0][1]), fmaxf(sc[0][2], sc[0][3])),
                       fmaxf(fmaxf(sc[1][0], sc[1][1]), fmaxf(sc[1][2], sc[1][3])));
      mx = fmaxf(mx, __shfl_xor(mx, 16));
      mx = fmaxf(mx, __shfl_xor(mx, 32));
      float mnew = fmaxf(m_run, mx);
      float alpha = __expf(m_run - mnew);   // row-uniform across quads
      m_run = mnew;

      float ps = 0.f;
      #pragma unroll
      for (int tile = 0; tile < 2; tile++)
        #pragma unroll
        for (int rr = 0; rr < 4; rr++){
          float e = __expf(sc[tile][rr] - mnew);
          sc[tile][rr] = e; ps += e;
        }
      l_lane = l_lane * alpha + ps;         // per-lane partial (final reduce after loop)

      #pragma unroll
      for (int g = 0; g < 4; g++)
        #pragma unroll
        for (int rr = 0; rr < 4; rr++) oacc[g][rr] *= alpha;   // per-lane: col m = l16

      // O^T += V^T x P^T : A = V^T-frag, B = P^T-frag (= S^T C-layout, as-is)
      #pragma unroll
      for (int tile = 0; tile < 2; tile++){
        f16x4 pf;
        #pragma unroll
        for (int rr = 0; rr < 4; rr++) pf[rr] = (_Float16)sc[tile][rr];
        #pragma unroll
        for (int g = 0; g < 4; g++){
          f16x4 av = *(const f16x4*)&Vs[buf][(g*16 + l16)*32 + (((tile*2 + (quad>>1)) ^ (l16 & 3))*8) + (quad & 1)*4];
          oacc[g] = __builtin_amdgcn_mfma_f32_16x16x16f16(av, pf, oacc[g], 0, 0, 0);
        }
      }
    }
  }

  // final l reduce (once) + per-lane normalize
  float l_tot = l_lane + __shfl_xor(l_lane, 16);
  l_tot += __shfl_xor(l_tot, 32);
  float linv = __builtin_amdgcn_rcpf(l_tot);

  // O^T[d][m]: store O[m=l16][d=g*16+quad*4+rr]; pack 4 bf16 = 8B per g
  size_t orow = (size_t)(b*SEQ + q0 + l16)*EMBED + h*HD;
  #pragma unroll
  for (int g = 0; g < 4; g++){
    ushort4 pk;
    pk.x = f2bf(oacc[g][0] * linv);
    pk.y = f2bf(oacc[g][1] * linv);
    pk.z = f2bf(oacc[g][2] * linv);
    pk.w = f2bf(oacc[g][3] * linv);
    *(ushort4*)&attn_out[orow + g*16 + quad*4] = pk;
  }
}

// ---------------- GEMM2: 128x128 tile, attn_out @ w_out + b_out -> fp32 ----------------

__global__ __launch_bounds__(256) void k_gemm_out(
    const unsigned short* __restrict__ A,    // [4096][1024] bf16
    const unsigned short* __restrict__ BT,   // [1024][1024] bf16
    const float* __restrict__ bias,          // [1024]
    float* __restrict__ out)
{
  __shared__ __align__(16) unsigned short As[128*32];
  __shared__ __align__(16) unsigned short Bs[128*32];
  const int K = EMBED;
  int m0 = blockIdx.x * 128, n0 = blockIdx.y * 128;
  int tid = threadIdx.x, lane = tid & 63, wave = tid >> 6;
  int wm = wave >> 1, wn = wave & 1;
  int l16 = lane & 15, quad = lane >> 4;
  f32x4 acc[4][4] = {};
  int c0i = wave*64 + lane, c1i = 256 + wave*64 + lane;
  int r0 = c0i >> 2, cc0 = (c0i & 3) * 8;
  int r1 = c1i >> 2, cc1 = (c1i & 3) * 8;
  unsigned short* lA0 = &As[(wave*64)*8];
  unsigned short* lA1 = &As[(256 + wave*64)*8];
  unsigned short* lB0 = &Bs[(wave*64)*8];
  unsigned short* lB1 = &Bs[(256 + wave*64)*8];
  for (int k0 = 0; k0 < K; k0 += 32){
    async_ld16((void*)&A [(size_t)(m0 + r0)*K + k0 + cc0], (void*)lA0);
    async_ld16((void*)&A [(size_t)(m0 + r1)*K + k0 + cc1], (void*)lA1);
    async_ld16((void*)&BT[(size_t)(n0 + r0)*K + k0 + cc0], (void*)lB0);
    async_ld16((void*)&BT[(size_t)(n0 + r1)*K + k0 + cc1], (void*)lB1);
    __syncthreads();
    bf16x8 af[4], bfr[4];
    #pragma unroll
    for (int mi = 0; mi < 4; mi++) af[mi]  = *(const bf16x8*)&As[(wm*64 + mi*16 + l16)*32 + quad*8];
    #pragma unroll
    for (int ni = 0; ni < 4; ni++) bfr[ni] = *(const bf16x8*)&Bs[(wn*64 + ni*16 + l16)*32 + quad*8];
    #pragma unroll
    for (int mi = 0; mi < 4; mi++)
      #pragma unroll
      for (int ni = 0; ni < 4; ni++)
        acc[mi][ni] = __builtin_amdgcn_mfma_f32_16x16x32_bf16(af[mi], bfr[ni], acc[mi][ni], 0, 0, 0);
    __syncthreads();
  }
  #pragma unroll
  for (int mi = 0; mi < 4; mi++)
    #pragma unroll
    for (int ni = 0; ni < 4; ni++)
      #pragma unroll
      for (int rr = 0; rr < 4; rr++){
        int row = m0 + wm*64 + mi*16 + quad*4 + rr;
        int col = n0 + wn*64 + ni*16 + l16;
        out[(size_t)row*EMBED + col] = acc[mi][ni][rr] + bias[col];
      }
}

// ---------------- launch ----------------

extern "C" void kernel_launch(void* const* d_in, const int* in_sizes, int n_in,
                              void* d_out, int out_size, void* d_ws, size_t ws_size,
                              hipStream_t stream) {
  const float* x     = (const float*)d_in[0];
  const float* w_qkv = (const float*)d_in[1];
  const float* b_qkv = (const float*)d_in[2];
  const float* w_out = (const float*)d_in[3];
  const float* b_out = (const float*)d_in[4];
  float* out = (float*)d_out;

  char* ws = (char*)d_ws;
  size_t off = 0;
  auto alloc = [&](size_t bytes) -> void* {
    void* p = ws + off; off += (bytes + 255) & ~(size_t)255; return p;
  };
  unsigned short* xb    = (unsigned short*)alloc((size_t)ROWS * EMBED * 2);      // 8 MB
  unsigned short* wqkvT = (unsigned short*)alloc((size_t)3 * EMBED * EMBED * 2); // 6 MB
  unsigned short* woutT = (unsigned short*)alloc((size_t)EMBED * EMBED * 2);     // 2 MB
  unsigned short* qb    = (unsigned short*)alloc((size_t)ROWS * EMBED * 2);
  unsigned short* kb    = (unsigned short*)alloc((size_t)ROWS * EMBED * 2);
  unsigned short* vb    = (unsigned short*)alloc((size_t)ROWS * EMBED * 2);      // f16 bits
  unsigned short* vTb   = (unsigned short*)alloc((size_t)ROWS * EMBED * 2);      // f16 bits
  float* qn = (float*)alloc((size_t)BHD * SEQ * 4);
  float* kn = (float*)alloc((size_t)BHD * SEQ * 4);
  unsigned short* attnb = xb;  // xb dead after GEMM1 — alias

  k_conv<<<dim3((ROWS*EMBED/4 + 255)/256), dim3(256), 0, stream>>>(x, xb, ROWS*EMBED/4);
  k_tr_f2b<<<dim3(3*EMBED/32, EMBED/32), dim3(32, 8), 0, stream>>>(w_qkv, wqkvT, EMBED, 3*EMBED);
  k_tr_f2b<<<dim3(EMBED/32, EMBED/32), dim3(32, 8), 0, stream>>>(w_out, woutT, EMBED, EMBED);
  k_gemm_qkv<<<dim3(ROWS/128, 3*EMBED/128), dim3(256), 0, stream>>>(xb, wqkvT, b_qkv, qb, kb, vb);
  k_norms<<<dim3(BHD*SEQ/256), dim3(256), 0, stream>>>(qb, kb, qn, kn);
  k_tr_b2b<<<dim3(HD/32, SEQ/32, BHD), dim3(32, 8), 0, stream>>>(vb, vTb, SEQ, HD);
  k_attn<<<dim3(32, BHD), dim3(256), 0, stream>>>(qb, kb, vTb, qn, kn, attnb);
  k_gemm_out<<<dim3(ROWS/128, EMBED/128), dim3(256), 0, stream>>>(attnb, woutT, b_out, out);
}

// Round 7
// 246.551 us; speedup vs baseline: 1.5814x; 1.1002x over previous
//
#include <hip/hip_runtime.h>

#define EMBED 1024
#define NH 16
#define HD 64
#define SEQ 2048
#define BATCH 2
#define ROWS (BATCH*SEQ)   // 4096
#define BHD (BATCH*NH)     // 32

typedef __bf16 bf16x8 __attribute__((ext_vector_type(8)));
typedef _Float16 f16x4 __attribute__((ext_vector_type(4)));
typedef float f32x4 __attribute__((ext_vector_type(4)));

__device__ __forceinline__ unsigned short f2bf(float f){
  union { float f; unsigned u; } v; v.f = f;
  unsigned r = v.u + 0x7fffu + ((v.u >> 16) & 1u);
  return (unsigned short)(r >> 16);
}
__device__ __forceinline__ float bf2f(unsigned short s){
  union { unsigned u; float f; } v; v.u = ((unsigned)s) << 16; return v.f;
}
__device__ __forceinline__ unsigned short f2h(float f){
  union { _Float16 h; unsigned short u; } v; v.h = (_Float16)f; return v.u;
}

// async global->LDS, 16B per lane; lds ptr must be wave-uniform base (lane*16 implicit)
typedef __attribute__((address_space(1))) unsigned int as1_t;
typedef __attribute__((address_space(3))) unsigned int as3_t;
__device__ __forceinline__ void async_ld16(const void* gp, void* lp){
  __builtin_amdgcn_global_load_lds((as1_t*)gp, (as3_t*)lp, 16, 0, 0);
}

// ---------------- prep kernels ----------------

__global__ __launch_bounds__(256) void k_conv(const float* __restrict__ x,
                                              unsigned short* __restrict__ xb, int n4){
  int i = blockIdx.x * blockDim.x + threadIdx.x;
  if (i < n4){
    float4 f = ((const float4*)x)[i];
    ushort4 o;
    o.x = f2bf(f.x); o.y = f2bf(f.y); o.z = f2bf(f.z); o.w = f2bf(f.w);
    ((ushort4*)xb)[i] = o;
  }
}

// in[R][C] fp32 -> out[C][R] bf16
__global__ __launch_bounds__(256) void k_tr_f2b(const float* __restrict__ in,
                                                unsigned short* __restrict__ out, int R, int C){
  __shared__ float t[32][33];
  int c0 = blockIdx.x * 32, r0 = blockIdx.y * 32;
  int tx = threadIdx.x, ty = threadIdx.y;
  #pragma unroll
  for (int i = 0; i < 4; i++){ int r = ty + i*8; t[r][tx] = in[(size_t)(r0+r)*C + c0 + tx]; }
  __syncthreads();
  #pragma unroll
  for (int i = 0; i < 4; i++){ int rr = ty + i*8; out[(size_t)(c0+rr)*R + r0 + tx] = f2bf(t[tx][rr]); }
}

// batched 16-bit transpose: in[batch][R][C] -> out[batch][C][R]
__global__ __launch_bounds__(256) void k_tr_b2b(const unsigned short* __restrict__ in,
                                                unsigned short* __restrict__ out, int R, int C){
  in  += (size_t)blockIdx.z * R * C;
  out += (size_t)blockIdx.z * R * C;
  __shared__ unsigned short t[32][33];
  int c0 = blockIdx.x * 32, r0 = blockIdx.y * 32;
  int tx = threadIdx.x, ty = threadIdx.y;
  #pragma unroll
  for (int i = 0; i < 4; i++){ int r = ty + i*8; t[r][tx] = in[(size_t)(r0+r)*C + c0 + tx]; }
  __syncthreads();
  #pragma unroll
  for (int i = 0; i < 4; i++){ int rr = ty + i*8; out[(size_t)(c0+rr)*R + r0 + tx] = t[tx][rr]; }
}

// qn/kn from bf16-rounded q,k (keeps denominator = |q~ - k~|^2 >= 0)
__global__ __launch_bounds__(256) void k_norms(const unsigned short* __restrict__ q,
                                               const unsigned short* __restrict__ k,
                                               float* __restrict__ qn, float* __restrict__ kn){
  int i = blockIdx.x * blockDim.x + threadIdx.x;  // [0, 65536)
  const uint4* qr = (const uint4*)(q + (size_t)i * HD);
  const uint4* kr = (const uint4*)(k + (size_t)i * HD);
  float sq = 0.f, sk = 0.f;
  #pragma unroll
  for (int t = 0; t < 8; t++){
    uint4 uq = qr[t], uk = kr[t];
    unsigned aq[4] = {uq.x, uq.y, uq.z, uq.w};
    unsigned ak[4] = {uk.x, uk.y, uk.z, uk.w};
    #pragma unroll
    for (int j = 0; j < 4; j++){
      float f0 = bf2f((unsigned short)(aq[j] & 0xffff));
      float f1 = bf2f((unsigned short)(aq[j] >> 16));
      sq += f0*f0 + f1*f1;
      float g0 = bf2f((unsigned short)(ak[j] & 0xffff));
      float g1 = bf2f((unsigned short)(ak[j] >> 16));
      sk += g0*g0 + g1*g1;
    }
  }
  qn[i] = sq; kn[i] = sk;
}

// ---------------- GEMM1: 128x128 tile, global_load_lds staging ----------------

__global__ __launch_bounds__(256) void k_gemm_qkv(
    const unsigned short* __restrict__ A,    // [4096][1024] bf16
    const unsigned short* __restrict__ BT,   // [3072][1024] bf16
    const float* __restrict__ bias,          // [3072]
    unsigned short* __restrict__ qo, unsigned short* __restrict__ ko,
    unsigned short* __restrict__ vo)
{
  __shared__ __align__(16) unsigned short As[128*32];
  __shared__ __align__(16) unsigned short Bs[128*32];
  const int K = EMBED;
  int m0 = blockIdx.x * 128, n0 = blockIdx.y * 128;
  int tid = threadIdx.x, lane = tid & 63, wave = tid >> 6;
  int wm = wave >> 1, wn = wave & 1;
  int l16 = lane & 15, quad = lane >> 4;
  f32x4 acc[4][4] = {};
  int c0i = wave*64 + lane, c1i = 256 + wave*64 + lane;
  int r0 = c0i >> 2, cc0 = (c0i & 3) * 8;
  int r1 = c1i >> 2, cc1 = (c1i & 3) * 8;
  unsigned short* lA0 = &As[(wave*64)*8];
  unsigned short* lA1 = &As[(256 + wave*64)*8];
  unsigned short* lB0 = &Bs[(wave*64)*8];
  unsigned short* lB1 = &Bs[(256 + wave*64)*8];
  for (int k0 = 0; k0 < K; k0 += 32){
    async_ld16((void*)&A [(size_t)(m0 + r0)*K + k0 + cc0], (void*)lA0);
    async_ld16((void*)&A [(size_t)(m0 + r1)*K + k0 + cc1], (void*)lA1);
    async_ld16((void*)&BT[(size_t)(n0 + r0)*K + k0 + cc0], (void*)lB0);
    async_ld16((void*)&BT[(size_t)(n0 + r1)*K + k0 + cc1], (void*)lB1);
    __syncthreads();
    bf16x8 af[4], bfr[4];
    #pragma unroll
    for (int mi = 0; mi < 4; mi++) af[mi]  = *(const bf16x8*)&As[(wm*64 + mi*16 + l16)*32 + quad*8];
    #pragma unroll
    for (int ni = 0; ni < 4; ni++) bfr[ni] = *(const bf16x8*)&Bs[(wn*64 + ni*16 + l16)*32 + quad*8];
    #pragma unroll
    for (int mi = 0; mi < 4; mi++)
      #pragma unroll
      for (int ni = 0; ni < 4; ni++)
        acc[mi][ni] = __builtin_amdgcn_mfma_f32_16x16x32_bf16(af[mi], bfr[ni], acc[mi][ni], 0, 0, 0);
    __syncthreads();
  }
  #pragma unroll
  for (int mi = 0; mi < 4; mi++)
    #pragma unroll
    for (int ni = 0; ni < 4; ni++)
      #pragma unroll
      for (int rr = 0; rr < 4; rr++){
        int row = m0 + wm*64 + mi*16 + quad*4 + rr;
        int col = n0 + wn*64 + ni*16 + l16;
        float val = acc[mi][ni][rr] + bias[col];
        int b = row >> 11, l = row & 2047;
        int which = col >> 10, e = col & 1023, h = e >> 6, d = e & 63;
        unsigned short* dst = which == 0 ? qo : (which == 1 ? ko : vo);
        unsigned short bits = (which == 2) ? f2h(val) : f2bf(val);
        dst[(((size_t)(b*NH + h))*SEQ + l)*HD + d] = bits;
      }
}

// ---------------- attention: 128-thr block = 2 waves over 32 q-rows, paired tiles {p,63-p} ----------------
// K LDS: 32 rows x 72 shorts (64 data + 8 pad) -> b128 read granule-col (9j+c)&7: conflict-free
// V LDS: 64 rows x 36 f16   (32 data + 4 pad) -> b64 read 8B-col (9d+c)&15, 9 coprime 16: conflict-free
// Staging: global->VGPR->ds_write (padding incompatible with global_load_lds DMA).
// O^T accumulation (R6): softmax row m on l16 everywhere; 2 shuffles/iter (running max only).

__global__ __launch_bounds__(128) void k_attn(
    const unsigned short* __restrict__ qg,   // [BH][L][D] bf16
    const unsigned short* __restrict__ kg,   // [BH][L][D] bf16
    const unsigned short* __restrict__ vtg,  // [BH][D][L] f16
    const float* __restrict__ qn,
    const float* __restrict__ kn,
    unsigned short* __restrict__ attn_out)   // [ROWS][EMBED] bf16
{
  __shared__ __align__(16) unsigned short Ks[2][32*72];  // 2 x 4.5 KB
  __shared__ __align__(16) _Float16      Vs[2][64*36];   // 2 x 4.5 KB
  int bh = blockIdx.y; int b = bh >> 4, h = bh & 15;
  int tid = threadIdx.x, lane = tid & 63, wave = tid >> 6;   // wave 0..1
  int l16 = lane & 15, quad = lane >> 4;
  int p = blockIdx.x;                  // pair id 0..31

  const unsigned short* qbase = qg  + (size_t)bh * SEQ * HD;
  const unsigned short* kbase = kg  + (size_t)bh * SEQ * HD;
  const _Float16*       vtb   = (const _Float16*)vtg + (size_t)bh * HD * SEQ;
  const float* knb = kn + (size_t)bh * SEQ;

  // staging map: thread stages K granules tid, tid+128 and V granules tid, tid+128
  int kd0 = tid >> 3,        kc0 = tid & 7;          // K rows 0..15
  int kd1 = (tid + 128) >> 3, kc1 = tid & 7;         // K rows 16..31
  int vd0 = tid >> 2,        vc0 = tid & 3;          // V rows 0..31
  int vd1 = 32 + (tid >> 2), vc1 = tid & 3;          // V rows 32..63

  #pragma unroll
  for (int pass = 0; pass < 2; pass++){
    int t = pass ? (63 - p) : p;       // 32-row tiles, paired for uniform 66 iters/block
    int q0 = t*32 + wave*16;
    int jmax_w = q0 + 16;
    int jmax_b = t*32 + 32;

    bf16x8 aq[2];
    #pragma unroll
    for (int sk = 0; sk < 2; sk++)
      aq[sk] = *(const bf16x8*)&qbase[(size_t)(q0 + l16)*HD + sk*32 + quad*8];
    float qn_m = qn[(size_t)bh*SEQ + q0 + l16];

    float m_run = -1e30f, l_lane = 0.f;
    f32x4 oacc[4] = {};

    // prologue: stage j-block 0 into buf 0
    {
      uint4 ka = *(const uint4*)&kbase[(size_t)kd0*HD + kc0*8];
      uint4 kb = *(const uint4*)&kbase[(size_t)kd1*HD + kc1*8];
      uint4 va = *(const uint4*)&vtb[(size_t)vd0*SEQ + vc0*8];
      uint4 vb = *(const uint4*)&vtb[(size_t)vd1*SEQ + vc1*8];
      *(uint4*)&Ks[0][kd0*72 + kc0*8] = ka;
      *(uint4*)&Ks[0][kd1*72 + kc1*8] = kb;
      *(uint2*)&Vs[0][vd0*36 + vc0*8]     = make_uint2(va.x, va.y);
      *(uint2*)&Vs[0][vd0*36 + vc0*8 + 4] = make_uint2(va.z, va.w);
      *(uint2*)&Vs[0][vd1*36 + vc1*8]     = make_uint2(vb.x, vb.y);
      *(uint2*)&Vs[0][vd1*36 + vc1*8 + 4] = make_uint2(vb.z, vb.w);
    }
    __syncthreads();

    for (int j0 = 0; j0 < jmax_b; j0 += 32){
      int buf = (j0 >> 5) & 1;
      // prefetch next j-block into VGPRs (clamped on last iter; written to buf^1, never read then)
      int jn = (j0 + 32 < jmax_b) ? j0 + 32 : j0;
      uint4 ka = *(const uint4*)&kbase[(size_t)(jn + kd0)*HD + kc0*8];
      uint4 kb = *(const uint4*)&kbase[(size_t)(jn + kd1)*HD + kc1*8];
      uint4 va = *(const uint4*)&vtb[(size_t)vd0*SEQ + jn + vc0*8];
      uint4 vb = *(const uint4*)&vtb[(size_t)vd1*SEQ + jn + vc1*8];

      if (j0 < jmax_w){
        // S^T: D = K(A) x Q(B); C-layout: m on l16, j on quad*4+rr
        f32x4 st[2] = {};
        #pragma unroll
        for (int tile = 0; tile < 2; tile++)
          #pragma unroll
          for (int sk = 0; sk < 2; sk++){
            bf16x8 ak = *(const bf16x8*)&Ks[buf][(tile*16 + l16)*72 + (sk*4 + quad)*8];
            st[tile] = __builtin_amdgcn_mfma_f32_16x16x32_bf16(ak, aq[sk], st[tile], 0, 0, 0);
          }
        float4 kn_a = *(const float4*)&knb[j0 + quad*4];
        float4 kn_b = *(const float4*)&knb[j0 + 16 + quad*4];
        float kn_j[2][4] = {{kn_a.x, kn_a.y, kn_a.z, kn_a.w}, {kn_b.x, kn_b.y, kn_b.z, kn_b.w}};
        int mg = q0 + l16;
        float sc[2][4];
        if (j0 + 32 > q0){  // wave-uniform: diagonal block -> mask
          #pragma unroll
          for (int tile = 0; tile < 2; tile++)
            #pragma unroll
            for (int rr = 0; rr < 4; rr++){
              int jg = j0 + tile*16 + quad*4 + rr;
              float dot = st[tile][rr];
              float den = fmaxf(qn_m + kn_j[tile][rr] - 2.0f*dot, 0.0f) + 1e-6f;
              float v = dot * dot * __builtin_amdgcn_rcpf(den);
              sc[tile][rr] = (jg <= mg) ? v : -1e30f;
            }
        } else {
          #pragma unroll
          for (int tile = 0; tile < 2; tile++)
            #pragma unroll
            for (int rr = 0; rr < 4; rr++){
              float dot = st[tile][rr];
              float den = fmaxf(qn_m + kn_j[tile][rr] - 2.0f*dot, 0.0f) + 1e-6f;
              sc[tile][rr] = dot * dot * __builtin_amdgcn_rcpf(den);
            }
        }
        float mx = fmaxf(fmaxf(fmaxf(sc[0][0], sc[0][1]), fmaxf(sc[0][2], sc[0][3])),
                         fmaxf(fmaxf(sc[1][0], sc[1][1]), fmaxf(sc[1][2], sc[1][3])));
        mx = fmaxf(mx, __shfl_xor(mx, 16));
        mx = fmaxf(mx, __shfl_xor(mx, 32));
        float mnew = fmaxf(m_run, mx);
        float alpha = __expf(m_run - mnew);
        m_run = mnew;

        float ps = 0.f;
        #pragma unroll
        for (int tile = 0; tile < 2; tile++)
          #pragma unroll
          for (int rr = 0; rr < 4; rr++){
            float e = __expf(sc[tile][rr] - mnew);
            sc[tile][rr] = e; ps += e;
          }
        l_lane = l_lane * alpha + ps;

        #pragma unroll
        for (int g = 0; g < 4; g++)
          #pragma unroll
          for (int rr = 0; rr < 4; rr++) oacc[g][rr] *= alpha;

        // O^T += V^T x P^T : A = V^T-frag, B = P^T-frag (= S^T C-layout, as-is)
        #pragma unroll
        for (int tile = 0; tile < 2; tile++){
          f16x4 pf;
          #pragma unroll
          for (int rr = 0; rr < 4; rr++) pf[rr] = (_Float16)sc[tile][rr];
          #pragma unroll
          for (int g = 0; g < 4; g++){
            f16x4 av = *(const f16x4*)&Vs[buf][(g*16 + l16)*36 + (tile*4 + quad)*4];
            oacc[g] = __builtin_amdgcn_mfma_f32_16x16x16f16(av, pf, oacc[g], 0, 0, 0);
          }
        }
      }

      // write prefetched data into buf^1 (not read this iter); barrier makes it visible
      *(uint4*)&Ks[buf^1][kd0*72 + kc0*8] = ka;
      *(uint4*)&Ks[buf^1][kd1*72 + kc1*8] = kb;
      *(uint2*)&Vs[buf^1][vd0*36 + vc0*8]     = make_uint2(va.x, va.y);
      *(uint2*)&Vs[buf^1][vd0*36 + vc0*8 + 4] = make_uint2(va.z, va.w);
      *(uint2*)&Vs[buf^1][vd1*36 + vc1*8]     = make_uint2(vb.x, vb.y);
      *(uint2*)&Vs[buf^1][vd1*36 + vc1*8 + 4] = make_uint2(vb.z, vb.w);
      __syncthreads();
    }

    // final l reduce + per-lane normalize; store O (O^T regs: d = g*16+quad*4+rr, m = l16)
    float l_tot = l_lane + __shfl_xor(l_lane, 16);
    l_tot += __shfl_xor(l_tot, 32);
    float linv = __builtin_amdgcn_rcpf(l_tot);

    size_t orow = (size_t)(b*SEQ + q0 + l16)*EMBED + h*HD;
    #pragma unroll
    for (int g = 0; g < 4; g++){
      ushort4 pk;
      pk.x = f2bf(oacc[g][0] * linv);
      pk.y = f2bf(oacc[g][1] * linv);
      pk.z = f2bf(oacc[g][2] * linv);
      pk.w = f2bf(oacc[g][3] * linv);
      *(ushort4*)&attn_out[orow + g*16 + quad*4] = pk;
    }
    __syncthreads();  // LDS reuse across passes
  }
}

// ---------------- GEMM2: 128x128 tile, attn_out @ w_out + b_out -> fp32 ----------------

__global__ __launch_bounds__(256) void k_gemm_out(
    const unsigned short* __restrict__ A,    // [4096][1024] bf16
    const unsigned short* __restrict__ BT,   // [1024][1024] bf16
    const float* __restrict__ bias,          // [1024]
    float* __restrict__ out)
{
  __shared__ __align__(16) unsigned short As[128*32];
  __shared__ __align__(16) unsigned short Bs[128*32];
  const int K = EMBED;
  int m0 = blockIdx.x * 128, n0 = blockIdx.y * 128;
  int tid = threadIdx.x, lane = tid & 63, wave = tid >> 6;
  int wm = wave >> 1, wn = wave & 1;
  int l16 = lane & 15, quad = lane >> 4;
  f32x4 acc[4][4] = {};
  int c0i = wave*64 + lane, c1i = 256 + wave*64 + lane;
  int r0 = c0i >> 2, cc0 = (c0i & 3) * 8;
  int r1 = c1i >> 2, cc1 = (c1i & 3) * 8;
  unsigned short* lA0 = &As[(wave*64)*8];
  unsigned short* lA1 = &As[(256 + wave*64)*8];
  unsigned short* lB0 = &Bs[(wave*64)*8];
  unsigned short* lB1 = &Bs[(256 + wave*64)*8];
  for (int k0 = 0; k0 < K; k0 += 32){
    async_ld16((void*)&A [(size_t)(m0 + r0)*K + k0 + cc0], (void*)lA0);
    async_ld16((void*)&A [(size_t)(m0 + r1)*K + k0 + cc1], (void*)lA1);
    async_ld16((void*)&BT[(size_t)(n0 + r0)*K + k0 + cc0], (void*)lB0);
    async_ld16((void*)&BT[(size_t)(n0 + r1)*K + k0 + cc1], (void*)lB1);
    __syncthreads();
    bf16x8 af[4], bfr[4];
    #pragma unroll
    for (int mi = 0; mi < 4; mi++) af[mi]  = *(const bf16x8*)&As[(wm*64 + mi*16 + l16)*32 + quad*8];
    #pragma unroll
    for (int ni = 0; ni < 4; ni++) bfr[ni] = *(const bf16x8*)&Bs[(wn*64 + ni*16 + l16)*32 + quad*8];
    #pragma unroll
    for (int mi = 0; mi < 4; mi++)
      #pragma unroll
      for (int ni = 0; ni < 4; ni++)
        acc[mi][ni] = __builtin_amdgcn_mfma_f32_16x16x32_bf16(af[mi], bfr[ni], acc[mi][ni], 0, 0, 0);
    __syncthreads();
  }
  #pragma unroll
  for (int mi = 0; mi < 4; mi++)
    #pragma unroll
    for (int ni = 0; ni < 4; ni++)
      #pragma unroll
      for (int rr = 0; rr < 4; rr++){
        int row = m0 + wm*64 + mi*16 + quad*4 + rr;
        int col = n0 + wn*64 + ni*16 + l16;
        out[(size_t)row*EMBED + col] = acc[mi][ni][rr] + bias[col];
      }
}

// ---------------- launch ----------------

extern "C" void kernel_launch(void* const* d_in, const int* in_sizes, int n_in,
                              void* d_out, int out_size, void* d_ws, size_t ws_size,
                              hipStream_t stream) {
  const float* x     = (const float*)d_in[0];
  const float* w_qkv = (const float*)d_in[1];
  const float* b_qkv = (const float*)d_in[2];
  const float* w_out = (const float*)d_in[3];
  const float* b_out = (const float*)d_in[4];
  float* out = (float*)d_out;

  char* ws = (char*)d_ws;
  size_t off = 0;
  auto alloc = [&](size_t bytes) -> void* {
    void* p = ws + off; off += (bytes + 255) & ~(size_t)255; return p;
  };
  unsigned short* xb    = (unsigned short*)alloc((size_t)ROWS * EMBED * 2);      // 8 MB
  unsigned short* wqkvT = (unsigned short*)alloc((size_t)3 * EMBED * EMBED * 2); // 6 MB
  unsigned short* woutT = (unsigned short*)alloc((size_t)EMBED * EMBED * 2);     // 2 MB
  unsigned short* qb    = (unsigned short*)alloc((size_t)ROWS * EMBED * 2);
  unsigned short* kb    = (unsigned short*)alloc((size_t)ROWS * EMBED * 2);
  unsigned short* vb    = (unsigned short*)alloc((size_t)ROWS * EMBED * 2);      // f16 bits
  unsigned short* vTb   = (unsigned short*)alloc((size_t)ROWS * EMBED * 2);      // f16 bits
  float* qn = (float*)alloc((size_t)BHD * SEQ * 4);
  float* kn = (float*)alloc((size_t)BHD * SEQ * 4);
  unsigned short* attnb = xb;  // xb dead after GEMM1 — alias

  k_conv<<<dim3((ROWS*EMBED/4 + 255)/256), dim3(256), 0, stream>>>(x, xb, ROWS*EMBED/4);
  k_tr_f2b<<<dim3(3*EMBED/32, EMBED/32), dim3(32, 8), 0, stream>>>(w_qkv, wqkvT, EMBED, 3*EMBED);
  k_tr_f2b<<<dim3(EMBED/32, EMBED/32), dim3(32, 8), 0, stream>>>(w_out, woutT, EMBED, EMBED);
  k_gemm_qkv<<<dim3(ROWS/128, 3*EMBED/128), dim3(256), 0, stream>>>(xb, wqkvT, b_qkv, qb, kb, vb);
  k_norms<<<dim3(BHD*SEQ/256), dim3(256), 0, stream>>>(qb, kb, qn, kn);
  k_tr_b2b<<<dim3(HD/32, SEQ/32, BHD), dim3(32, 8), 0, stream>>>(vb, vTb, SEQ, HD);
  k_attn<<<dim3(32, BHD), dim3(128), 0, stream>>>(qb, kb, vTb, qn, kn, attnb);
  k_gemm_out<<<dim3(ROWS/128, EMBED/128), dim3(256), 0, stream>>>(attnb, woutT, b_out, out);
}

// Round 8
// 222.432 us; speedup vs baseline: 1.7528x; 1.1084x over previous
//
#include <hip/hip_runtime.h>

#define EMBED 1024
#define NH 16
#define HD 64
#define SEQ 2048
#define BATCH 2
#define ROWS (BATCH*SEQ)   // 4096
#define BHD (BATCH*NH)     // 32

typedef __bf16 bf16x8 __attribute__((ext_vector_type(8)));
typedef _Float16 f16x4 __attribute__((ext_vector_type(4)));
typedef float f32x4 __attribute__((ext_vector_type(4)));

__device__ __forceinline__ unsigned short f2bf(float f){
  union { float f; unsigned u; } v; v.f = f;
  unsigned r = v.u + 0x7fffu + ((v.u >> 16) & 1u);
  return (unsigned short)(r >> 16);
}
__device__ __forceinline__ float bf2f(unsigned short s){
  union { unsigned u; float f; } v; v.u = ((unsigned)s) << 16; return v.f;
}
__device__ __forceinline__ unsigned short f2h(float f){
  union { _Float16 h; unsigned short u; } v; v.h = (_Float16)f; return v.u;
}

// async global->LDS, 16B per lane; lds ptr must be wave-uniform base (lane*16 implicit)
typedef __attribute__((address_space(1))) unsigned int as1_t;
typedef __attribute__((address_space(3))) unsigned int as3_t;
__device__ __forceinline__ void async_ld16(const void* gp, void* lp){
  __builtin_amdgcn_global_load_lds((as1_t*)gp, (as3_t*)lp, 16, 0, 0);
}

// ---------------- prep kernels ----------------

__global__ __launch_bounds__(256) void k_conv(const float* __restrict__ x,
                                              unsigned short* __restrict__ xb, int n4){
  int i = blockIdx.x * blockDim.x + threadIdx.x;
  if (i < n4){
    float4 f = ((const float4*)x)[i];
    ushort4 o;
    o.x = f2bf(f.x); o.y = f2bf(f.y); o.z = f2bf(f.z); o.w = f2bf(f.w);
    ((ushort4*)xb)[i] = o;
  }
}

// in[R][C] fp32 -> out[C][R] bf16
__global__ __launch_bounds__(256) void k_tr_f2b(const float* __restrict__ in,
                                                unsigned short* __restrict__ out, int R, int C){
  __shared__ float t[32][33];
  int c0 = blockIdx.x * 32, r0 = blockIdx.y * 32;
  int tx = threadIdx.x, ty = threadIdx.y;
  #pragma unroll
  for (int i = 0; i < 4; i++){ int r = ty + i*8; t[r][tx] = in[(size_t)(r0+r)*C + c0 + tx]; }
  __syncthreads();
  #pragma unroll
  for (int i = 0; i < 4; i++){ int rr = ty + i*8; out[(size_t)(c0+rr)*R + r0 + tx] = f2bf(t[tx][rr]); }
}

// batched 16-bit transpose: in[batch][R][C] -> out[batch][C][R]
__global__ __launch_bounds__(256) void k_tr_b2b(const unsigned short* __restrict__ in,
                                                unsigned short* __restrict__ out, int R, int C){
  in  += (size_t)blockIdx.z * R * C;
  out += (size_t)blockIdx.z * R * C;
  __shared__ unsigned short t[32][33];
  int c0 = blockIdx.x * 32, r0 = blockIdx.y * 32;
  int tx = threadIdx.x, ty = threadIdx.y;
  #pragma unroll
  for (int i = 0; i < 4; i++){ int r = ty + i*8; t[r][tx] = in[(size_t)(r0+r)*C + c0 + tx]; }
  __syncthreads();
  #pragma unroll
  for (int i = 0; i < 4; i++){ int rr = ty + i*8; out[(size_t)(c0+rr)*R + r0 + tx] = t[tx][rr]; }
}

// qn/kn from bf16-rounded q,k (keeps denominator = |q~ - k~|^2 >= 0)
__global__ __launch_bounds__(256) void k_norms(const unsigned short* __restrict__ q,
                                               const unsigned short* __restrict__ k,
                                               float* __restrict__ qn, float* __restrict__ kn){
  int i = blockIdx.x * blockDim.x + threadIdx.x;  // [0, 65536)
  const uint4* qr = (const uint4*)(q + (size_t)i * HD);
  const uint4* kr = (const uint4*)(k + (size_t)i * HD);
  float sq = 0.f, sk = 0.f;
  #pragma unroll
  for (int t = 0; t < 8; t++){
    uint4 uq = qr[t], uk = kr[t];
    unsigned aq[4] = {uq.x, uq.y, uq.z, uq.w};
    unsigned ak[4] = {uk.x, uk.y, uk.z, uk.w};
    #pragma unroll
    for (int j = 0; j < 4; j++){
      float f0 = bf2f((unsigned short)(aq[j] & 0xffff));
      float f1 = bf2f((unsigned short)(aq[j] >> 16));
      sq += f0*f0 + f1*f1;
      float g0 = bf2f((unsigned short)(ak[j] & 0xffff));
      float g1 = bf2f((unsigned short)(ak[j] >> 16));
      sk += g0*g0 + g1*g1;
    }
  }
  qn[i] = sq; kn[i] = sk;
}

// ---------------- GEMM1: 128x128 tile, global_load_lds staging ----------------

__global__ __launch_bounds__(256) void k_gemm_qkv(
    const unsigned short* __restrict__ A,    // [4096][1024] bf16
    const unsigned short* __restrict__ BT,   // [3072][1024] bf16
    const float* __restrict__ bias,          // [3072]
    unsigned short* __restrict__ qo, unsigned short* __restrict__ ko,
    unsigned short* __restrict__ vo)
{
  __shared__ __align__(16) unsigned short As[128*32];
  __shared__ __align__(16) unsigned short Bs[128*32];
  const int K = EMBED;
  int m0 = blockIdx.x * 128, n0 = blockIdx.y * 128;
  int tid = threadIdx.x, lane = tid & 63, wave = tid >> 6;
  int wm = wave >> 1, wn = wave & 1;
  int l16 = lane & 15, quad = lane >> 4;
  f32x4 acc[4][4] = {};
  int c0i = wave*64 + lane, c1i = 256 + wave*64 + lane;
  int r0 = c0i >> 2, cc0 = (c0i & 3) * 8;
  int r1 = c1i >> 2, cc1 = (c1i & 3) * 8;
  unsigned short* lA0 = &As[(wave*64)*8];
  unsigned short* lA1 = &As[(256 + wave*64)*8];
  unsigned short* lB0 = &Bs[(wave*64)*8];
  unsigned short* lB1 = &Bs[(256 + wave*64)*8];
  for (int k0 = 0; k0 < K; k0 += 32){
    async_ld16((void*)&A [(size_t)(m0 + r0)*K + k0 + cc0], (void*)lA0);
    async_ld16((void*)&A [(size_t)(m0 + r1)*K + k0 + cc1], (void*)lA1);
    async_ld16((void*)&BT[(size_t)(n0 + r0)*K + k0 + cc0], (void*)lB0);
    async_ld16((void*)&BT[(size_t)(n0 + r1)*K + k0 + cc1], (void*)lB1);
    __syncthreads();
    bf16x8 af[4], bfr[4];
    #pragma unroll
    for (int mi = 0; mi < 4; mi++) af[mi]  = *(const bf16x8*)&As[(wm*64 + mi*16 + l16)*32 + quad*8];
    #pragma unroll
    for (int ni = 0; ni < 4; ni++) bfr[ni] = *(const bf16x8*)&Bs[(wn*64 + ni*16 + l16)*32 + quad*8];
    #pragma unroll
    for (int mi = 0; mi < 4; mi++)
      #pragma unroll
      for (int ni = 0; ni < 4; ni++)
        acc[mi][ni] = __builtin_amdgcn_mfma_f32_16x16x32_bf16(af[mi], bfr[ni], acc[mi][ni], 0, 0, 0);
    __syncthreads();
  }
  #pragma unroll
  for (int mi = 0; mi < 4; mi++)
    #pragma unroll
    for (int ni = 0; ni < 4; ni++)
      #pragma unroll
      for (int rr = 0; rr < 4; rr++){
        int row = m0 + wm*64 + mi*16 + quad*4 + rr;
        int col = n0 + wn*64 + ni*16 + l16;
        float val = acc[mi][ni][rr] + bias[col];
        int b = row >> 11, l = row & 2047;
        int which = col >> 10, e = col & 1023, h = e >> 6, d = e & 63;
        unsigned short* dst = which == 0 ? qo : (which == 1 ? ko : vo);
        unsigned short bits = (which == 2) ? f2h(val) : f2bf(val);
        dst[(((size_t)(b*NH + h))*SEQ + l)*HD + d] = bits;
      }
}

// ---------------- attention: block (P,s) = j-segment s of tile pair {P, 63-P} ----------------
// R7 structure (2 waves over 32 q-rows, padded LDS, shared ds_write staging, O^T accum)
// + j-split x2 for 2x occupancy. Partials: UNNORMALIZED O^T (f32) + m + l, merged by k_combine.

__global__ __launch_bounds__(128, 4) void k_attn(
    const unsigned short* __restrict__ qg,   // [BH][L][D] bf16
    const unsigned short* __restrict__ kg,   // [BH][L][D] bf16
    const unsigned short* __restrict__ vtg,  // [BH][D][L] f16
    const float* __restrict__ qn,
    const float* __restrict__ kn,
    float* __restrict__ Opart,               // [BH*64 tiles][2 segs][32 r][64 d] f32
    float* __restrict__ Mp,                  // [BH*64][2][32]
    float* __restrict__ Lp)                  // [BH*64][2][32]
{
  __shared__ __align__(16) unsigned short Ks[2][32*72];  // 2 x 4.5 KB (64 data + 8 pad shorts/row)
  __shared__ __align__(16) _Float16      Vs[2][64*36];   // 2 x 4.5 KB (32 data + 4 pad f16/row)
  int bh = blockIdx.y;
  int tid = threadIdx.x, lane = tid & 63, wave = tid >> 6;   // wave 0..1
  int l16 = lane & 15, quad = lane >> 4;
  int P = blockIdx.x >> 1, s = blockIdx.x & 1;   // pair 0..31, segment 0..1

  const unsigned short* qbase = qg  + (size_t)bh * SEQ * HD;
  const unsigned short* kbase = kg  + (size_t)bh * SEQ * HD;
  const _Float16*       vtb   = (const _Float16*)vtg + (size_t)bh * HD * SEQ;
  const float* knb = kn + (size_t)bh * SEQ;

  // staging map: thread stages K granules tid, tid+128 and V granules tid, tid+128
  int kd0 = tid >> 3,         kc0 = tid & 7;     // K rows 0..15
  int kd1 = (tid + 128) >> 3, kc1 = tid & 7;     // K rows 16..31
  int vd0 = tid >> 2,         vc0 = tid & 3;     // V rows 0..31
  int vd1 = 32 + (tid >> 2),  vc1 = tid & 3;     // V rows 32..63

  #pragma unroll
  for (int pass = 0; pass < 2; pass++){
    int t = pass ? (63 - P) : P;       // 32-row tile
    int nj = t + 1;                    // j-blocks in this tile's causal extent
    int half = (nj + 1) >> 1;
    int jb_lo = s ? half : 0;
    int jb_hi = s ? nj : half;
    int q0 = t*32 + wave*16;

    bf16x8 aq[2];
    #pragma unroll
    for (int sk = 0; sk < 2; sk++)
      aq[sk] = *(const bf16x8*)&qbase[(size_t)(q0 + l16)*HD + sk*32 + quad*8];
    float qn_m = qn[(size_t)bh*SEQ + q0 + l16];

    float m_run = -1e30f, l_lane = 0.f;
    f32x4 oacc[4] = {};

    if (jb_lo < jb_hi){
      int jlo = jb_lo * 32;
      // prologue: stage first j-block into buf 0
      {
        uint4 ka = *(const uint4*)&kbase[(size_t)(jlo + kd0)*HD + kc0*8];
        uint4 kb = *(const uint4*)&kbase[(size_t)(jlo + kd1)*HD + kc1*8];
        uint4 va = *(const uint4*)&vtb[(size_t)vd0*SEQ + jlo + vc0*8];
        uint4 vb = *(const uint4*)&vtb[(size_t)vd1*SEQ + jlo + vc1*8];
        *(uint4*)&Ks[0][kd0*72 + kc0*8] = ka;
        *(uint4*)&Ks[0][kd1*72 + kc1*8] = kb;
        *(uint2*)&Vs[0][vd0*36 + vc0*8]     = make_uint2(va.x, va.y);
        *(uint2*)&Vs[0][vd0*36 + vc0*8 + 4] = make_uint2(va.z, va.w);
        *(uint2*)&Vs[0][vd1*36 + vc1*8]     = make_uint2(vb.x, vb.y);
        *(uint2*)&Vs[0][vd1*36 + vc1*8 + 4] = make_uint2(vb.z, vb.w);
      }
      __syncthreads();

      for (int jb = jb_lo; jb < jb_hi; jb++){
        int j0 = jb * 32;
        int buf = (jb - jb_lo) & 1;
        // prefetch next j-block into VGPRs (clamped; written to buf^1, never read then)
        int jn = (jb + 1 < jb_hi) ? (jb + 1)*32 : j0;
        uint4 ka = *(const uint4*)&kbase[(size_t)(jn + kd0)*HD + kc0*8];
        uint4 kb = *(const uint4*)&kbase[(size_t)(jn + kd1)*HD + kc1*8];
        uint4 va = *(const uint4*)&vtb[(size_t)vd0*SEQ + jn + vc0*8];
        uint4 vb = *(const uint4*)&vtb[(size_t)vd1*SEQ + jn + vc1*8];

        // S^T: D = K(A) x Q(B); C-layout: m on l16, j on quad*4+rr
        f32x4 st[2] = {};
        #pragma unroll
        for (int tile = 0; tile < 2; tile++)
          #pragma unroll
          for (int sk = 0; sk < 2; sk++){
            bf16x8 ak = *(const bf16x8*)&Ks[buf][(tile*16 + l16)*72 + (sk*4 + quad)*8];
            st[tile] = __builtin_amdgcn_mfma_f32_16x16x32_bf16(ak, aq[sk], st[tile], 0, 0, 0);
          }
        float4 kn_a = *(const float4*)&knb[j0 + quad*4];
        float4 kn_b = *(const float4*)&knb[j0 + 16 + quad*4];
        float kn_j[2][4] = {{kn_a.x, kn_a.y, kn_a.z, kn_a.w}, {kn_b.x, kn_b.y, kn_b.z, kn_b.w}};
        int mg = q0 + l16;
        float sc[2][4];
        if (j0 + 32 > q0){  // wave-uniform: diagonal block -> mask
          #pragma unroll
          for (int tile = 0; tile < 2; tile++)
            #pragma unroll
            for (int rr = 0; rr < 4; rr++){
              int jg = j0 + tile*16 + quad*4 + rr;
              float dot = st[tile][rr];
              float den = fmaxf(qn_m + kn_j[tile][rr] - 2.0f*dot, 0.0f) + 1e-6f;
              float v = dot * dot * __builtin_amdgcn_rcpf(den);
              sc[tile][rr] = (jg <= mg) ? v : -1e30f;
            }
        } else {
          #pragma unroll
          for (int tile = 0; tile < 2; tile++)
            #pragma unroll
            for (int rr = 0; rr < 4; rr++){
              float dot = st[tile][rr];
              float den = fmaxf(qn_m + kn_j[tile][rr] - 2.0f*dot, 0.0f) + 1e-6f;
              sc[tile][rr] = dot * dot * __builtin_amdgcn_rcpf(den);
            }
        }
        float mx = fmaxf(fmaxf(fmaxf(sc[0][0], sc[0][1]), fmaxf(sc[0][2], sc[0][3])),
                         fmaxf(fmaxf(sc[1][0], sc[1][1]), fmaxf(sc[1][2], sc[1][3])));
        mx = fmaxf(mx, __shfl_xor(mx, 16));
        mx = fmaxf(mx, __shfl_xor(mx, 32));
        float mnew = fmaxf(m_run, mx);
        float alpha = __expf(m_run - mnew);
        m_run = mnew;

        float ps = 0.f;
        #pragma unroll
        for (int tile = 0; tile < 2; tile++)
          #pragma unroll
          for (int rr = 0; rr < 4; rr++){
            float e = __expf(sc[tile][rr] - mnew);
            sc[tile][rr] = e; ps += e;
          }
        l_lane = l_lane * alpha + ps;

        #pragma unroll
        for (int g = 0; g < 4; g++)
          #pragma unroll
          for (int rr = 0; rr < 4; rr++) oacc[g][rr] *= alpha;

        // O^T += V^T x P^T : A = V^T-frag, B = P^T-frag (= S^T C-layout, as-is)
        #pragma unroll
        for (int tile = 0; tile < 2; tile++){
          f16x4 pf;
          #pragma unroll
          for (int rr = 0; rr < 4; rr++) pf[rr] = (_Float16)sc[tile][rr];
          #pragma unroll
          for (int g = 0; g < 4; g++){
            f16x4 av = *(const f16x4*)&Vs[buf][(g*16 + l16)*36 + (tile*4 + quad)*4];
            oacc[g] = __builtin_amdgcn_mfma_f32_16x16x16f16(av, pf, oacc[g], 0, 0, 0);
          }
        }

        // write prefetched data into buf^1; barrier makes it visible
        *(uint4*)&Ks[buf^1][kd0*72 + kc0*8] = ka;
        *(uint4*)&Ks[buf^1][kd1*72 + kc1*8] = kb;
        *(uint2*)&Vs[buf^1][vd0*36 + vc0*8]     = make_uint2(va.x, va.y);
        *(uint2*)&Vs[buf^1][vd0*36 + vc0*8 + 4] = make_uint2(va.z, va.w);
        *(uint2*)&Vs[buf^1][vd1*36 + vc1*8]     = make_uint2(vb.x, vb.y);
        *(uint2*)&Vs[buf^1][vd1*36 + vc1*8 + 4] = make_uint2(vb.z, vb.w);
        __syncthreads();
      }
    }

    // reduce l across quads (2 shuffles, once per pass)
    float l_tot = l_lane + __shfl_xor(l_lane, 16);
    l_tot += __shfl_xor(l_tot, 32);

    // write UNNORMALIZED partials: O^T regs (d = g*16+quad*4+rr, m = l16) -> Opart[r][d]
    int r = wave*16 + l16;
    size_t pb = ((size_t)(bh*64 + t)*2 + s) * (32*64);
    #pragma unroll
    for (int g = 0; g < 4; g++){
      float4 pk = make_float4(oacc[g][0], oacc[g][1], oacc[g][2], oacc[g][3]);
      *(float4*)&Opart[pb + (size_t)r*64 + g*16 + quad*4] = pk;
    }
    if (quad == 0){
      int mb = ((bh*64 + t)*2 + s)*32 + r;
      Mp[mb] = m_run;
      Lp[mb] = l_tot;
    }
    __syncthreads();  // LDS reuse across passes
  }
}

// ---------------- combine the 2 j-segments per tile ----------------

__global__ __launch_bounds__(256) void k_combine(
    const float* __restrict__ Opart,
    const float* __restrict__ Mp,
    const float* __restrict__ Lp,
    unsigned short* __restrict__ attn_out)
{
  int t = blockIdx.x;             // tile 0..63
  int bh = blockIdx.y; int b = bh >> 4, h = bh & 15;
  int tid = threadIdx.x;
  int d = tid & 63, r8 = (tid >> 6) * 8;
  size_t i0 = ((size_t)(bh*64 + t)*2) * 2048;   // seg0: 32*64 floats
  size_t i1 = i0 + 2048;
  int mb = ((bh*64 + t)*2) * 32;
  #pragma unroll
  for (int rr = 0; rr < 8; rr++){
    int r = r8 + rr;
    float m0 = Mp[mb + r],      m1 = Mp[mb + 32 + r];
    float l0 = Lp[mb + r],      l1 = Lp[mb + 32 + r];
    float ms = fmaxf(m0, m1);
    float w0 = __expf(m0 - ms), w1 = __expf(m1 - ms);
    float den = w0*l0 + w1*l1;
    float o = (w0*Opart[i0 + (size_t)r*64 + d] + w1*Opart[i1 + (size_t)r*64 + d]) / den;
    attn_out[(size_t)(b*SEQ + t*32 + r)*EMBED + h*HD + d] = f2bf(o);
  }
}

// ---------------- GEMM2: 128x128 tile, attn_out @ w_out + b_out -> fp32 ----------------

__global__ __launch_bounds__(256) void k_gemm_out(
    const unsigned short* __restrict__ A,    // [4096][1024] bf16
    const unsigned short* __restrict__ BT,   // [1024][1024] bf16
    const float* __restrict__ bias,          // [1024]
    float* __restrict__ out)
{
  __shared__ __align__(16) unsigned short As[128*32];
  __shared__ __align__(16) unsigned short Bs[128*32];
  const int K = EMBED;
  int m0 = blockIdx.x * 128, n0 = blockIdx.y * 128;
  int tid = threadIdx.x, lane = tid & 63, wave = tid >> 6;
  int wm = wave >> 1, wn = wave & 1;
  int l16 = lane & 15, quad = lane >> 4;
  f32x4 acc[4][4] = {};
  int c0i = wave*64 + lane, c1i = 256 + wave*64 + lane;
  int r0 = c0i >> 2, cc0 = (c0i & 3) * 8;
  int r1 = c1i >> 2, cc1 = (c1i & 3) * 8;
  unsigned short* lA0 = &As[(wave*64)*8];
  unsigned short* lA1 = &As[(256 + wave*64)*8];
  unsigned short* lB0 = &Bs[(wave*64)*8];
  unsigned short* lB1 = &Bs[(256 + wave*64)*8];
  for (int k0 = 0; k0 < K; k0 += 32){
    async_ld16((void*)&A [(size_t)(m0 + r0)*K + k0 + cc0], (void*)lA0);
    async_ld16((void*)&A [(size_t)(m0 + r1)*K + k0 + cc1], (void*)lA1);
    async_ld16((void*)&BT[(size_t)(n0 + r0)*K + k0 + cc0], (void*)lB0);
    async_ld16((void*)&BT[(size_t)(n0 + r1)*K + k0 + cc1], (void*)lB1);
    __syncthreads();
    bf16x8 af[4], bfr[4];
    #pragma unroll
    for (int mi = 0; mi < 4; mi++) af[mi]  = *(const bf16x8*)&As[(wm*64 + mi*16 + l16)*32 + quad*8];
    #pragma unroll
    for (int ni = 0; ni < 4; ni++) bfr[ni] = *(const bf16x8*)&Bs[(wn*64 + ni*16 + l16)*32 + quad*8];
    #pragma unroll
    for (int mi = 0; mi < 4; mi++)
      #pragma unroll
      for (int ni = 0; ni < 4; ni++)
        acc[mi][ni] = __builtin_amdgcn_mfma_f32_16x16x32_bf16(af[mi], bfr[ni], acc[mi][ni], 0, 0, 0);
    __syncthreads();
  }
  #pragma unroll
  for (int mi = 0; mi < 4; mi++)
    #pragma unroll
    for (int ni = 0; ni < 4; ni++)
      #pragma unroll
      for (int rr = 0; rr < 4; rr++){
        int row = m0 + wm*64 + mi*16 + quad*4 + rr;
        int col = n0 + wn*64 + ni*16 + l16;
        out[(size_t)row*EMBED + col] = acc[mi][ni][rr] + bias[col];
      }
}

// ---------------- launch ----------------

extern "C" void kernel_launch(void* const* d_in, const int* in_sizes, int n_in,
                              void* d_out, int out_size, void* d_ws, size_t ws_size,
                              hipStream_t stream) {
  const float* x     = (const float*)d_in[0];
  const float* w_qkv = (const float*)d_in[1];
  const float* b_qkv = (const float*)d_in[2];
  const float* w_out = (const float*)d_in[3];
  const float* b_out = (const float*)d_in[4];
  float* out = (float*)d_out;

  char* ws = (char*)d_ws;
  size_t off = 0;
  auto alloc = [&](size_t bytes) -> void* {
    void* p = ws + off; off += (bytes + 255) & ~(size_t)255; return p;
  };
  unsigned short* xb    = (unsigned short*)alloc((size_t)ROWS * EMBED * 2);      // 8 MB
  unsigned short* wqkvT = (unsigned short*)alloc((size_t)3 * EMBED * EMBED * 2); // 6 MB
  unsigned short* woutT = (unsigned short*)alloc((size_t)EMBED * EMBED * 2);     // 2 MB
  unsigned short* qb    = (unsigned short*)alloc((size_t)ROWS * EMBED * 2);
  unsigned short* kb    = (unsigned short*)alloc((size_t)ROWS * EMBED * 2);
  unsigned short* vb    = (unsigned short*)alloc((size_t)ROWS * EMBED * 2);      // f16 bits
  unsigned short* vTb   = (unsigned short*)alloc((size_t)ROWS * EMBED * 2);      // f16 bits
  float* qn = (float*)alloc((size_t)BHD * SEQ * 4);
  float* kn = (float*)alloc((size_t)BHD * SEQ * 4);
  float* Opart = (float*)alloc((size_t)BHD * 64 * 2 * 32 * 64 * 4);              // 33.5 MB
  float* Mp    = (float*)alloc((size_t)BHD * 64 * 2 * 32 * 4);                   // 0.5 MB
  float* Lp    = (float*)alloc((size_t)BHD * 64 * 2 * 32 * 4);                   // 0.5 MB
  unsigned short* attnb = xb;  // xb dead after GEMM1 — alias

  k_conv<<<dim3((ROWS*EMBED/4 + 255)/256), dim3(256), 0, stream>>>(x, xb, ROWS*EMBED/4);
  k_tr_f2b<<<dim3(3*EMBED/32, EMBED/32), dim3(32, 8), 0, stream>>>(w_qkv, wqkvT, EMBED, 3*EMBED);
  k_tr_f2b<<<dim3(EMBED/32, EMBED/32), dim3(32, 8), 0, stream>>>(w_out, woutT, EMBED, EMBED);
  k_gemm_qkv<<<dim3(ROWS/128, 3*EMBED/128), dim3(256), 0, stream>>>(xb, wqkvT, b_qkv, qb, kb, vb);
  k_norms<<<dim3(BHD*SEQ/256), dim3(256), 0, stream>>>(qb, kb, qn, kn);
  k_tr_b2b<<<dim3(HD/32, SEQ/32, BHD), dim3(32, 8), 0, stream>>>(vb, vTb, SEQ, HD);
  k_attn<<<dim3(64, BHD), dim3(128), 0, stream>>>(qb, kb, vTb, qn, kn, Opart, Mp, Lp);
  k_combine<<<dim3(64, BHD), dim3(256), 0, stream>>>(Opart, Mp, Lp, attnb);
  k_gemm_out<<<dim3(ROWS/128, EMBED/128), dim3(256), 0, stream>>>(attnb, woutT, b_out, out);
}